// Round 5
// baseline (974.992 us; speedup 1.0000x reference)
//
#include <hip/hip_runtime.h>
#include <math.h>

#define DD 128
#define NRANGE 128
#define MAXRW 512

typedef __attribute__((ext_vector_type(8))) short bf16x8;  // 8 bf16 (4 VGPR)
typedef __attribute__((ext_vector_type(4))) float f32x4;   // 4 fp32 acc

__device__ __forceinline__ ushort f2bf(float f) {
    union { float f; unsigned u; } v; v.f = f;
    unsigned r = v.u + 0x7fff + ((v.u >> 16) & 1);   // RNE
    return (ushort)(r >> 16);
}

__device__ __forceinline__ float2 bfp(unsigned u) {
    union { unsigned x; float f; } a, b;
    a.x = u << 16;
    b.x = u & 0xffff0000u;
    return make_float2(a.f, b.f);
}

// ==================== weight prep (once per launch) ====================
__global__ __launch_bounds__(256) void combine_all(const float* __restrict__ qkv_w,
                                                   const float* __restrict__ qkv_b,
                                                   const float* __restrict__ edge_W,
                                                   float* __restrict__ WC,
                                                   float* __restrict__ BCq)
{
    const int z = blockIdx.y;          // (L<<1)|t
    const int L = z >> 1, t = z & 1;
    const float* wq = qkv_w + (((size_t)L * 2 + t) * 3 + 0) * DD * DD;
    const float* bq = qkv_b + (((size_t)L * 2 + t) * 3 + 0) * DD;
    const float* We = edge_W + ((size_t)L * 2 + t) * DD * DD;
    float* Wz = WC + (size_t)z * DD * DD;
    float* Bz = BCq + (size_t)z * DD;

    const int tid = threadIdx.x;
    const int i = blockIdx.x * 2 + (tid >> 7);
    const int j = tid & 127;
    float sum = 0.f;
    for (int k = 0; k < DD; ++k) sum = fmaf(wq[i * DD + k], We[k * DD + j], sum);
    Wz[i * DD + j] = sum;
    if (blockIdx.x == 0 && tid < DD) {
        float s2 = 0.f;
        for (int k = 0; k < DD; ++k) s2 = fmaf(bq[k], We[k * DD + j], s2);
        Bz[j] = s2;
    }
}

__global__ __launch_bounds__(256) void pack_all(const float* __restrict__ qkv_w,
                                                const float* __restrict__ qkv_b,
                                                const float* __restrict__ WC,
                                                const float* __restrict__ BCq,
                                                ushort* __restrict__ W3P,
                                                float* __restrict__ B3)
{
    const int z = blockIdx.y;
    const int L = z >> 1, t = z & 1;
    const int ci = blockIdx.x * 256 + threadIdx.x;     // 0..6143
    const int cb = ci >> 11;
    const int ct = (ci >> 8) & 7;
    const int ks = (ci >> 6) & 3;
    const int l  = ci & 63;
    const int c3 = cb * 128 + ct * 16 + (l & 15);
    const int k0 = ks * 32 + (l >> 4) * 8;

    const float* wv = qkv_w + (((size_t)L * 2 + t) * 3 + 2) * DD * DD;
    const float* wk = qkv_w + (((size_t)L * 2 + (t ^ 1)) * 3 + 1) * DD * DD;
    const float* src;
    int cc;
    if (c3 < 128)      { src = WC + (size_t)z * DD * DD; cc = c3; }
    else if (c3 < 256) { src = wv; cc = c3 - 128; }
    else               { src = wk; cc = c3 - 256; }

    ushort h[8];
    #pragma unroll
    for (int j = 0; j < 8; ++j) h[j] = f2bf(src[(size_t)(k0 + j) * DD + cc]);
    ushort* dst = W3P + (size_t)z * 6144 * 8 + (size_t)ci * 8;
    #pragma unroll
    for (int j = 0; j < 8; ++j) dst[j] = h[j];

    if (ci < 384) {
        float bv;
        if (ci < 128)      bv = BCq[(size_t)z * DD + ci];
        else if (ci < 256) bv = qkv_b[(((size_t)L * 2 + t) * 3 + 2) * DD + (ci - 128)];
        else               bv = qkv_b[(((size_t)L * 2 + (t ^ 1)) * 3 + 1) * DD + (ci - 256)];
        B3[(size_t)z * 384 + ci] = bv;
    }
}

// ==================== fused MFMA GEMM (bf16 output) ====================
template<bool RELU_IN>
__global__ __launch_bounds__(256) void gemm_mfma(const float* __restrict__ Xsrc,
                                                 const float* __restrict__ Xdst,
                                                 const ushort* __restrict__ Bp,
                                                 const float* __restrict__ bias,
                                                 ushort* __restrict__ outbase,
                                                 int N)
{
    const int by = blockIdx.y;
    const float* X = (by == 2) ? Xdst : Xsrc;
    const ushort* Bz = Bp + (size_t)by * 16384;
    const float* bz = bias + by * 128;
    ushort* out = outbase + (size_t)by * N * DD;

    __shared__ ushort As[1024 * 8];
    __shared__ ushort Bs[2048 * 8];

    const int tid  = threadIdx.x;
    const int row0 = blockIdx.x * 64;

    #pragma unroll
    for (int i = 0; i < 8; ++i) {
        int c = tid + i * 256;
        *(float4*)&Bs[(size_t)c * 8] = ((const float4*)Bz)[c];
    }

    {
        const int r = tid >> 2;
        const int q = tid & 3;
        const int grow = row0 + r;
        const bool ok = grow < N;
        const float* xr = X + (size_t)grow * DD;
        #pragma unroll
        for (int i = 0; i < 4; ++i) {
            const int k8 = q + i * 4;
            const int k  = k8 * 8;
            float4 v0 = make_float4(0.f,0.f,0.f,0.f), v1 = v0;
            if (ok) {
                v0 = *(const float4*)&xr[k];
                v1 = *(const float4*)&xr[k + 4];
                if (RELU_IN) {
                    v0.x=fmaxf(v0.x,0.f); v0.y=fmaxf(v0.y,0.f); v0.z=fmaxf(v0.z,0.f); v0.w=fmaxf(v0.w,0.f);
                    v1.x=fmaxf(v1.x,0.f); v1.y=fmaxf(v1.y,0.f); v1.z=fmaxf(v1.z,0.f); v1.w=fmaxf(v1.w,0.f);
                }
            }
            bf16x8 h;
            h[0]=(short)f2bf(v0.x); h[1]=(short)f2bf(v0.y); h[2]=(short)f2bf(v0.z); h[3]=(short)f2bf(v0.w);
            h[4]=(short)f2bf(v1.x); h[5]=(short)f2bf(v1.y); h[6]=(short)f2bf(v1.z); h[7]=(short)f2bf(v1.w);
            const int ks = k >> 5;
            const int l  = (r & 15) + 16 * (k8 & 3);
            const int c  = (r >> 4) * 256 + ks * 64 + l;
            *(bf16x8*)&As[(size_t)c * 8] = h;
        }
    }
    __syncthreads();

    const int wave = tid >> 6;
    const int lane = tid & 63;

    bf16x8 a[4];
    #pragma unroll
    for (int ks = 0; ks < 4; ++ks)
        a[ks] = *(const bf16x8*)&As[(size_t)(wave * 256 + ks * 64 + lane) * 8];

    f32x4 acc[8];
    #pragma unroll
    for (int ct = 0; ct < 8; ++ct) {
        acc[ct] = (f32x4){0.f, 0.f, 0.f, 0.f};
        #pragma unroll
        for (int ks = 0; ks < 4; ++ks) {
            bf16x8 b = *(const bf16x8*)&Bs[(size_t)((ct * 4 + ks) * 64 + lane) * 8];
            acc[ct] = __builtin_amdgcn_mfma_f32_16x16x32_bf16(a[ks], b, acc[ct], 0, 0, 0);
        }
    }

    const int rbase = row0 + wave * 16 + (lane >> 4) * 4;
    #pragma unroll
    for (int ct = 0; ct < 8; ++ct) {
        const int col = ct * 16 + (lane & 15);
        const float bv = bz[col];
        #pragma unroll
        for (int j = 0; j < 4; ++j) {
            const int rr = rbase + j;
            if (rr < N) out[(size_t)rr * DD + col] = f2bf(acc[ct][j] + bv);
        }
    }
}

// ==================== CSR build (range-partitioned, LDS counters) ====================
// grid (NRANGE, 2): block (r,t) owns dst range [r*rw, r*rw+rw) of edge type t.
__global__ __launch_bounds__(256) void csr_count(const int* __restrict__ dst0,
                                                 const int* __restrict__ dst1,
                                                 int* __restrict__ deg2,
                                                 int* __restrict__ rtot,
                                                 int nE, int N, int rw)
{
    const int r = blockIdx.x, t = blockIdx.y;
    const int lo = r * rw;
    const int hi = min(lo + rw, N);
    const int W  = hi - lo;
    if (W <= 0) { if (threadIdx.x == 0) rtot[t * NRANGE + r] = 0; return; }
    __shared__ int cnt[MAXRW];
    __shared__ int red[256];
    for (int i = threadIdx.x; i < W; i += 256) cnt[i] = 0;
    __syncthreads();
    const int* dst = t ? dst1 : dst0;
    const int4* d4 = (const int4*)dst;
    const int e4 = nE >> 2;
    for (int i = threadIdx.x; i < e4; i += 256) {
        int4 v = d4[i];
        if ((unsigned)(v.x - lo) < (unsigned)W) atomicAdd(&cnt[v.x - lo], 1);
        if ((unsigned)(v.y - lo) < (unsigned)W) atomicAdd(&cnt[v.y - lo], 1);
        if ((unsigned)(v.z - lo) < (unsigned)W) atomicAdd(&cnt[v.z - lo], 1);
        if ((unsigned)(v.w - lo) < (unsigned)W) atomicAdd(&cnt[v.w - lo], 1);
    }
    for (int e = (e4 << 2) + threadIdx.x; e < nE; e += 256) {
        int v = dst[e];
        if ((unsigned)(v - lo) < (unsigned)W) atomicAdd(&cnt[v - lo], 1);
    }
    __syncthreads();
    int* deg = deg2 + (size_t)t * N;
    int tot = 0;
    for (int i = threadIdx.x; i < W; i += 256) { int c = cnt[i]; deg[lo + i] = c; tot += c; }
    red[threadIdx.x] = tot;
    __syncthreads();
    for (int s = 128; s > 0; s >>= 1) {
        if (threadIdx.x < s) red[threadIdx.x] += red[threadIdx.x + s];
        __syncthreads();
    }
    if (threadIdx.x == 0) rtot[t * NRANGE + r] = red[0];
}

// one block: segmented exclusive scan of 2x128 range totals
__global__ __launch_bounds__(256) void csr_scan_ranges(const int* __restrict__ rtot,
                                                       int* __restrict__ rbase,
                                                       int* __restrict__ offs0,
                                                       int* __restrict__ offs1, int N)
{
    __shared__ int tmp[256];
    const int tid = threadIdx.x;
    int v = rtot[tid];
    tmp[tid] = v;
    __syncthreads();
    for (int off = 1; off < NRANGE; off <<= 1) {
        int add = ((tid & (NRANGE - 1)) >= off) ? tmp[tid - off] : 0;
        __syncthreads();
        tmp[tid] += add;
        __syncthreads();
    }
    rbase[tid] = tmp[tid] - v;
    if (tid == NRANGE - 1) offs0[N] = tmp[tid];
    if (tid == 255)        offs1[N] = tmp[tid];
}

__global__ __launch_bounds__(256) void csr_fill(const int* __restrict__ src0,
                                                const int* __restrict__ dst0,
                                                const int* __restrict__ src1,
                                                const int* __restrict__ dst1,
                                                const int* __restrict__ deg2,
                                                const int* __restrict__ rbase,
                                                int* __restrict__ offs0,
                                                int* __restrict__ offs1,
                                                int* __restrict__ col0,
                                                int* __restrict__ col1,
                                                int nE, int N, int rw)
{
    const int r = blockIdx.x, t = blockIdx.y;
    const int lo = r * rw;
    const int hi = min(lo + rw, N);
    const int W  = hi - lo;
    if (W <= 0) return;
    __shared__ int cur[MAXRW];
    __shared__ int tmp[MAXRW];
    const int* deg = deg2 + (size_t)t * N;
    const int tid = threadIdx.x;

    for (int i = tid; i < MAXRW; i += 256) tmp[i] = (i < W) ? deg[lo + i] : 0;
    __syncthreads();
    // inclusive Hillis-Steele over MAXRW slots, 2 elems/thread
    for (int off = 1; off < MAXRW; off <<= 1) {
        const int i0 = tid, i1 = tid + 256;
        int a0 = (i0 >= off) ? tmp[i0 - off] : 0;
        int a1 = (i1 >= off) ? tmp[i1 - off] : 0;
        __syncthreads();
        tmp[i0] += a0;
        tmp[i1] += a1;
        __syncthreads();
    }
    const int base = rbase[t * NRANGE + r];
    int* offs = t ? offs1 : offs0;
    for (int i = tid; i < W; i += 256) {
        int excl = base + tmp[i] - deg[lo + i];
        cur[i] = excl;
        offs[lo + i] = excl;
    }
    __syncthreads();

    const int* src = t ? src1 : src0;
    const int* dst = t ? dst1 : dst0;
    int* col = t ? col1 : col0;
    const int4* d4 = (const int4*)dst;
    const int e4 = nE >> 2;
    for (int i = tid; i < e4; i += 256) {
        int4 v = d4[i];
        int e = i << 2;
        if ((unsigned)(v.x - lo) < (unsigned)W) { int p = atomicAdd(&cur[v.x - lo], 1); col[p] = src[e]; }
        if ((unsigned)(v.y - lo) < (unsigned)W) { int p = atomicAdd(&cur[v.y - lo], 1); col[p] = src[e + 1]; }
        if ((unsigned)(v.z - lo) < (unsigned)W) { int p = atomicAdd(&cur[v.z - lo], 1); col[p] = src[e + 2]; }
        if ((unsigned)(v.w - lo) < (unsigned)W) { int p = atomicAdd(&cur[v.w - lo], 1); col[p] = src[e + 3]; }
    }
    for (int e = (e4 << 2) + tid; e < nE; e += 256) {
        int v = dst[e];
        if ((unsigned)(v - lo) < (unsigned)W) { int p = atomicAdd(&cur[v - lo], 1); col[p] = src[e]; }
    }
}

// ==================== fused attention (bf16 gather, online softmax) ====================
__global__ __launch_bounds__(256) void attn_gather(const ushort* __restrict__ QW,
                                                   const ushort* __restrict__ K,
                                                   const ushort* __restrict__ V,
                                                   const int* __restrict__ offs,
                                                   const int* __restrict__ col,
                                                   float* __restrict__ out, int n)
{
    int wid  = (blockIdx.x * 256 + threadIdx.x) >> 6;
    int lane = threadIdx.x & 63;
    if (wid >= n) return;

    int beg = offs[wid], end = offs[wid + 1];
    float2 kf = bfp(((const unsigned*)(K + (size_t)wid * DD))[lane]);

    float m = -__builtin_inff();
    float den = 0.f;
    float2 acc = make_float2(0.f, 0.f);

    unsigned qn = 0, vn = 0;
    if (beg < end) {
        int s0 = col[beg];
        qn = ((const unsigned*)(QW + (size_t)s0 * DD))[lane];
        vn = ((const unsigned*)(V  + (size_t)s0 * DD))[lane];
    }

    for (int p = beg; p < end; ++p) {
        unsigned qu = qn, vu = vn;
        if (p + 1 < end) {
            int s2 = col[p + 1];
            qn = ((const unsigned*)(QW + (size_t)s2 * DD))[lane];
            vn = ((const unsigned*)(V  + (size_t)s2 * DD))[lane];
        }
        float2 qf = bfp(qu);
        float part = qf.x * kf.x + qf.y * kf.y;
        part += __shfl_xor(part, 1);
        part += __shfl_xor(part, 2);
        part += __shfl_xor(part, 4);
        part += __shfl_xor(part, 8);
        part += __shfl_xor(part, 16);
        part += __shfl_xor(part, 32);
        float sc = part * 0.08838834764831845f;      // 1/sqrt(128)
        sc = sc > 0.f ? sc : 0.01f * sc;             // leaky_relu
        float nm = fmaxf(m, sc);
        float f  = __expf(m - nm);
        float pe = __expf(sc - nm);
        float2 vf = bfp(vu);
        den   = den * f + pe;
        acc.x = acc.x * f + pe * vf.x;
        acc.y = acc.y * f + pe * vf.y;
        m = nm;
    }

    float inv = den > 0.f ? 1.f / den : 0.f;
    ((float2*)(out + (size_t)wid * DD))[lane] = make_float2(acc.x * inv, acc.y * inv);
}

// ==================== host ====================
extern "C" void kernel_launch(void* const* d_in, const int* in_sizes, int n_in,
                              void* d_out, int out_size, void* d_ws, size_t ws_size,
                              hipStream_t stream)
{
    const float* x_a    = (const float*)d_in[0];
    const float* x_b    = (const float*)d_in[1];
    const int*   ei_ab  = (const int*)d_in[2];
    const int*   ei_ba  = (const int*)d_in[3];
    const float* qkv_w  = (const float*)d_in[4];
    const float* qkv_b  = (const float*)d_in[5];
    const float* edge_W = (const float*)d_in[6];
    float* out = (float*)d_out;

    const int N = in_sizes[0] / DD;    // 50000
    const int E = in_sizes[2] / 2;     // 600000

    float* ws = (float*)d_ws;
    float* HA = ws;                          // layer-1 out a [N*D] f32
    float* HB = HA + (size_t)N * DD;         // layer-1 out b [N*D] f32
    float* WC  = HB + (size_t)N * DD;        // 4*128*128 f32
    float* BCq = WC + 4 * DD * DD;           // 4*128 f32
    float* B3  = BCq + 4 * DD;               // 4*384 f32
    ushort* W3P = (ushort*)(B3 + 4 * 384);   // 4*6144*8 bf16
    ushort* FQ = W3P + (size_t)4 * 6144 * 8; // q [N*D] bf16
    ushort* FV = FQ + (size_t)N * DD;        // v
    ushort* FK = FV + (size_t)N * DD;        // k
    int* ip      = (int*)(FK + (size_t)N * DD);
    int* deg2    = ip;                           // [2N]
    int* rtot    = deg2 + 2 * (size_t)N;         // [256]
    int* rbase   = rtot + 256;                   // [256]
    int* offs_ab = rbase + 256;                  // [N+1]
    int* offs_ba = offs_ab + (N + 1);            // [N+1]
    int* col_ab  = offs_ba + (N + 1);            // [E]
    int* col_ba  = col_ab + E;                   // [E]

    // ---- weight prep ----
    {
        dim3 g1(64, 4);
        combine_all<<<g1, 256, 0, stream>>>(qkv_w, qkv_b, edge_W, WC, BCq);
        dim3 g2(24, 4);
        pack_all<<<g2, 256, 0, stream>>>(qkv_w, qkv_b, WC, BCq, W3P, B3);
    }

    // ---- CSR (range-partitioned; reused by both layers) ----
    const int* s_ab = ei_ab;  const int* d_ab = ei_ab + E;
    const int* s_ba = ei_ba;  const int* d_ba = ei_ba + E;
    const int rw = (N + NRANGE - 1) / NRANGE;   // 391 for N=50000 (<= MAXRW)
    {
        dim3 cg(NRANGE, 2);
        csr_count<<<cg, 256, 0, stream>>>(d_ab, d_ba, deg2, rtot, E, N, rw);
        csr_scan_ranges<<<1, 256, 0, stream>>>(rtot, rbase, offs_ab, offs_ba, N);
        csr_fill<<<cg, 256, 0, stream>>>(s_ab, d_ab, s_ba, d_ba, deg2, rbase,
                                         offs_ab, offs_ba, col_ab, col_ba, E, N, rw);
    }

    const dim3 gemm_grid((N + 63) / 64, 3);
    const int ag_grid = (N + 3) / 4;

    auto attend = [&](int z, const float* Xsrc, const float* Xdst, bool relu_in,
                      const int* offs, const int* col, float* outbuf) {
        const ushort* Bp = W3P + (size_t)z * 6144 * 8;
        const float* bz  = B3 + (size_t)z * 384;
        if (relu_in)
            gemm_mfma<true ><<<gemm_grid, 256, 0, stream>>>(Xsrc, Xdst, Bp, bz, FQ, N);
        else
            gemm_mfma<false><<<gemm_grid, 256, 0, stream>>>(Xsrc, Xdst, Bp, bz, FQ, N);
        attn_gather<<<ag_grid, 256, 0, stream>>>(FQ, FK, FV, offs, col, outbuf, N);
    };

    // layer 1
    attend(0, x_a, x_b, false, offs_ab, col_ab, HB);   // a->b, dst b
    attend(1, x_b, x_a, false, offs_ba, col_ba, HA);   // b->a, dst a
    // layer 2 (relu fused into GEMM A-stage)
    float* o_a = out;
    float* o_b = out + (size_t)N * DD;
    attend(2, HA, HB, true, offs_ab, col_ab, o_b);
    attend(3, HB, HA, true, offs_ba, col_ba, o_a);
}

// Round 6
// 593.313 us; speedup vs baseline: 1.6433x; 1.6433x over previous
//
#include <hip/hip_runtime.h>
#include <math.h>

#define DD 128

typedef __attribute__((ext_vector_type(8))) short bf16x8;  // 8 bf16 (4 VGPR)
typedef __attribute__((ext_vector_type(4))) float f32x4;   // 4 fp32 acc

__device__ __forceinline__ ushort f2bf(float f) {
    union { float f; unsigned u; } v; v.f = f;
    unsigned r = v.u + 0x7fff + ((v.u >> 16) & 1);   // RNE
    return (ushort)(r >> 16);
}

__device__ __forceinline__ float2 bfp(unsigned u) {
    union { unsigned x; float f; } a, b;
    a.x = u << 16;
    b.x = u & 0xffff0000u;
    return make_float2(a.f, b.f);
}

// ==================== weight prep (once per launch) ====================
__global__ __launch_bounds__(256) void combine_all(const float* __restrict__ qkv_w,
                                                   const float* __restrict__ qkv_b,
                                                   const float* __restrict__ edge_W,
                                                   float* __restrict__ WC,
                                                   float* __restrict__ BCq)
{
    const int z = blockIdx.y;          // (L<<1)|t
    const int L = z >> 1, t = z & 1;
    const float* wq = qkv_w + (((size_t)L * 2 + t) * 3 + 0) * DD * DD;
    const float* bq = qkv_b + (((size_t)L * 2 + t) * 3 + 0) * DD;
    const float* We = edge_W + ((size_t)L * 2 + t) * DD * DD;
    float* Wz = WC + (size_t)z * DD * DD;
    float* Bz = BCq + (size_t)z * DD;

    const int tid = threadIdx.x;
    const int i = blockIdx.x * 2 + (tid >> 7);
    const int j = tid & 127;
    float sum = 0.f;
    for (int k = 0; k < DD; ++k) sum = fmaf(wq[i * DD + k], We[k * DD + j], sum);
    Wz[i * DD + j] = sum;
    if (blockIdx.x == 0 && tid < DD) {
        float s2 = 0.f;
        for (int k = 0; k < DD; ++k) s2 = fmaf(bq[k], We[k * DD + j], s2);
        Bz[j] = s2;
    }
}

__global__ __launch_bounds__(256) void pack_all(const float* __restrict__ qkv_w,
                                                const float* __restrict__ qkv_b,
                                                const float* __restrict__ WC,
                                                const float* __restrict__ BCq,
                                                ushort* __restrict__ W3P,
                                                float* __restrict__ B3)
{
    const int z = blockIdx.y;
    const int L = z >> 1, t = z & 1;
    const int ci = blockIdx.x * 256 + threadIdx.x;     // 0..6143
    const int cb = ci >> 11;
    const int ct = (ci >> 8) & 7;
    const int ks = (ci >> 6) & 3;
    const int l  = ci & 63;
    const int c3 = cb * 128 + ct * 16 + (l & 15);
    const int k0 = ks * 32 + (l >> 4) * 8;

    const float* wv = qkv_w + (((size_t)L * 2 + t) * 3 + 2) * DD * DD;
    const float* wk = qkv_w + (((size_t)L * 2 + (t ^ 1)) * 3 + 1) * DD * DD;
    const float* src;
    int cc;
    if (c3 < 128)      { src = WC + (size_t)z * DD * DD; cc = c3; }
    else if (c3 < 256) { src = wv; cc = c3 - 128; }
    else               { src = wk; cc = c3 - 256; }

    ushort h[8];
    #pragma unroll
    for (int j = 0; j < 8; ++j) h[j] = f2bf(src[(size_t)(k0 + j) * DD + cc]);
    ushort* dst = W3P + (size_t)z * 6144 * 8 + (size_t)ci * 8;
    #pragma unroll
    for (int j = 0; j < 8; ++j) dst[j] = h[j];

    if (ci < 384) {
        float bv;
        if (ci < 128)      bv = BCq[(size_t)z * DD + ci];
        else if (ci < 256) bv = qkv_b[(((size_t)L * 2 + t) * 3 + 2) * DD + (ci - 128)];
        else               bv = qkv_b[(((size_t)L * 2 + (t ^ 1)) * 3 + 1) * DD + (ci - 256)];
        B3[(size_t)z * 384 + ci] = bv;
    }
}

// ==================== fused MFMA GEMM (bf16 output) ====================
template<bool RELU_IN>
__global__ __launch_bounds__(256) void gemm_mfma(const float* __restrict__ Xsrc,
                                                 const float* __restrict__ Xdst,
                                                 const ushort* __restrict__ Bp,
                                                 const float* __restrict__ bias,
                                                 ushort* __restrict__ outbase,
                                                 int N)
{
    const int by = blockIdx.y;
    const float* X = (by == 2) ? Xdst : Xsrc;
    const ushort* Bz = Bp + (size_t)by * 16384;
    const float* bz = bias + by * 128;
    ushort* out = outbase + (size_t)by * N * DD;

    __shared__ ushort As[1024 * 8];
    __shared__ ushort Bs[2048 * 8];

    const int tid  = threadIdx.x;
    const int row0 = blockIdx.x * 64;

    #pragma unroll
    for (int i = 0; i < 8; ++i) {
        int c = tid + i * 256;
        *(float4*)&Bs[(size_t)c * 8] = ((const float4*)Bz)[c];
    }

    {
        const int r = tid >> 2;
        const int q = tid & 3;
        const int grow = row0 + r;
        const bool ok = grow < N;
        const float* xr = X + (size_t)grow * DD;
        #pragma unroll
        for (int i = 0; i < 4; ++i) {
            const int k8 = q + i * 4;
            const int k  = k8 * 8;
            float4 v0 = make_float4(0.f,0.f,0.f,0.f), v1 = v0;
            if (ok) {
                v0 = *(const float4*)&xr[k];
                v1 = *(const float4*)&xr[k + 4];
                if (RELU_IN) {
                    v0.x=fmaxf(v0.x,0.f); v0.y=fmaxf(v0.y,0.f); v0.z=fmaxf(v0.z,0.f); v0.w=fmaxf(v0.w,0.f);
                    v1.x=fmaxf(v1.x,0.f); v1.y=fmaxf(v1.y,0.f); v1.z=fmaxf(v1.z,0.f); v1.w=fmaxf(v1.w,0.f);
                }
            }
            bf16x8 h;
            h[0]=(short)f2bf(v0.x); h[1]=(short)f2bf(v0.y); h[2]=(short)f2bf(v0.z); h[3]=(short)f2bf(v0.w);
            h[4]=(short)f2bf(v1.x); h[5]=(short)f2bf(v1.y); h[6]=(short)f2bf(v1.z); h[7]=(short)f2bf(v1.w);
            const int ks = k >> 5;
            const int l  = (r & 15) + 16 * (k8 & 3);
            const int c  = (r >> 4) * 256 + ks * 64 + l;
            *(bf16x8*)&As[(size_t)c * 8] = h;
        }
    }
    __syncthreads();

    const int wave = tid >> 6;
    const int lane = tid & 63;

    bf16x8 a[4];
    #pragma unroll
    for (int ks = 0; ks < 4; ++ks)
        a[ks] = *(const bf16x8*)&As[(size_t)(wave * 256 + ks * 64 + lane) * 8];

    f32x4 acc[8];
    #pragma unroll
    for (int ct = 0; ct < 8; ++ct) {
        acc[ct] = (f32x4){0.f, 0.f, 0.f, 0.f};
        #pragma unroll
        for (int ks = 0; ks < 4; ++ks) {
            bf16x8 b = *(const bf16x8*)&Bs[(size_t)((ct * 4 + ks) * 64 + lane) * 8];
            acc[ct] = __builtin_amdgcn_mfma_f32_16x16x32_bf16(a[ks], b, acc[ct], 0, 0, 0);
        }
    }

    const int rbase = row0 + wave * 16 + (lane >> 4) * 4;
    #pragma unroll
    for (int ct = 0; ct < 8; ++ct) {
        const int col = ct * 16 + (lane & 15);
        const float bv = bz[col];
        #pragma unroll
        for (int j = 0; j < 4; ++j) {
            const int rr = rbase + j;
            if (rr < N) out[(size_t)rr * DD + col] = f2bf(acc[ct][j] + bv);
        }
    }
}

// ==================== CSR build (global atomics + hierarchical scan) ====================
__global__ __launch_bounds__(256) void zero_ints(int* __restrict__ p, int n)
{
    int i = blockIdx.x * 256 + threadIdx.x;
    if (i < n) p[i] = 0;
}

__global__ __launch_bounds__(256) void count_deg(const int* __restrict__ dab,
                                                 const int* __restrict__ dba,
                                                 int* __restrict__ degab,
                                                 int* __restrict__ degba, int nE)
{
    int e = blockIdx.x * 256 + threadIdx.x;
    if (e < nE) {
        atomicAdd(&degab[dab[e]], 1);
        atomicAdd(&degba[dba[e]], 1);
    }
}

// phase 1: grid (nb, 2); block sums 1024 deg entries
__global__ __launch_bounds__(256) void scan_p1(const int* __restrict__ deg2,
                                               int* __restrict__ part, int N, int nb)
{
    const int t = blockIdx.y;
    const int* deg = deg2 + (size_t)t * N;
    const int idx = blockIdx.x * 1024 + threadIdx.x * 4;
    int s = 0;
    if (idx + 3 < N) {
        int4 v = *(const int4*)&deg[idx];
        s = v.x + v.y + v.z + v.w;
    } else {
        for (int j = 0; j < 4; ++j) if (idx + j < N) s += deg[idx + j];
    }
    __shared__ int red[256];
    red[threadIdx.x] = s;
    __syncthreads();
    for (int st = 128; st > 0; st >>= 1) {
        if (threadIdx.x < st) red[threadIdx.x] += red[threadIdx.x + st];
        __syncthreads();
    }
    if (threadIdx.x == 0) part[t * nb + blockIdx.x] = red[0];
}

// phase 2: one block; exclusive scan of the 2 x nb partials (in place); totals -> offs[N]
__global__ __launch_bounds__(128) void scan_p2(int* __restrict__ part, int nb,
                                               int* __restrict__ offs0,
                                               int* __restrict__ offs1, int N)
{
    __shared__ int tmp[256];
    const int tid = threadIdx.x;
    for (int i = tid; i < 2 * nb; i += 128) tmp[i] = part[i];
    __syncthreads();
    if (tid < 2) {
        int run = 0;
        for (int i = 0; i < nb; ++i) { int v = tmp[tid * nb + i]; tmp[tid * nb + i] = run; run += v; }
        if (tid == 0) offs0[N] = run; else offs1[N] = run;
    }
    __syncthreads();
    for (int i = tid; i < 2 * nb; i += 128) part[i] = tmp[i];
}

// phase 3: grid (nb, 2); local scan of 1024-chunk, write offs + cursor
__global__ __launch_bounds__(256) void scan_p3(const int* __restrict__ deg2,
                                               const int* __restrict__ part,
                                               int* __restrict__ offs0,
                                               int* __restrict__ offs1,
                                               int* __restrict__ cur0,
                                               int* __restrict__ cur1, int N, int nb)
{
    const int t = blockIdx.y;
    const int* deg = deg2 + (size_t)t * N;
    int* offs = t ? offs1 : offs0;
    int* cur  = t ? cur1 : cur0;
    const int idx = blockIdx.x * 1024 + threadIdx.x * 4;
    int4 v = make_int4(0, 0, 0, 0);
    if (idx + 3 < N) v = *(const int4*)&deg[idx];
    else {
        int tv[4] = {0,0,0,0};
        for (int j = 0; j < 4; ++j) if (idx + j < N) tv[j] = deg[idx + j];
        v.x = tv[0]; v.y = tv[1]; v.z = tv[2]; v.w = tv[3];
    }
    const int tsum = v.x + v.y + v.z + v.w;
    __shared__ int sc[256];
    sc[threadIdx.x] = tsum;
    __syncthreads();
    for (int off = 1; off < 256; off <<= 1) {
        int add = (threadIdx.x >= off) ? sc[threadIdx.x - off] : 0;
        __syncthreads();
        sc[threadIdx.x] += add;
        __syncthreads();
    }
    int o0 = part[t * nb + blockIdx.x] + sc[threadIdx.x] - tsum;
    int o1 = o0 + v.x, o2 = o1 + v.y, o3 = o2 + v.z;
    if (idx + 3 < N) {
        *(int4*)&offs[idx] = make_int4(o0, o1, o2, o3);
        *(int4*)&cur[idx]  = make_int4(o0, o1, o2, o3);
    } else {
        int oo[4] = {o0, o1, o2, o3};
        for (int j = 0; j < 4; ++j) if (idx + j < N) { offs[idx + j] = oo[j]; cur[idx + j] = oo[j]; }
    }
}

__global__ __launch_bounds__(256) void fill_csr(const int* __restrict__ sab,
                                                const int* __restrict__ dab,
                                                const int* __restrict__ sba,
                                                const int* __restrict__ dba,
                                                int* __restrict__ curab,
                                                int* __restrict__ curba,
                                                int* __restrict__ colab,
                                                int* __restrict__ colba, int nE)
{
    int e = blockIdx.x * 256 + threadIdx.x;
    if (e < nE) {
        int p = atomicAdd(&curab[dab[e]], 1);
        colab[p] = sab[e];
        int q = atomicAdd(&curba[dba[e]], 1);
        colba[q] = sba[e];
    }
}

// ==================== fused attention (bf16 gather, online softmax) ====================
__global__ __launch_bounds__(256) void attn_gather(const ushort* __restrict__ QW,
                                                   const ushort* __restrict__ K,
                                                   const ushort* __restrict__ V,
                                                   const int* __restrict__ offs,
                                                   const int* __restrict__ col,
                                                   float* __restrict__ out, int n)
{
    int wid  = (blockIdx.x * 256 + threadIdx.x) >> 6;
    int lane = threadIdx.x & 63;
    if (wid >= n) return;

    int beg = offs[wid], end = offs[wid + 1];
    float2 kf = bfp(((const unsigned*)(K + (size_t)wid * DD))[lane]);

    float m = -__builtin_inff();
    float den = 0.f;
    float2 acc = make_float2(0.f, 0.f);

    unsigned qn = 0, vn = 0;
    if (beg < end) {
        int s0 = col[beg];
        qn = ((const unsigned*)(QW + (size_t)s0 * DD))[lane];
        vn = ((const unsigned*)(V  + (size_t)s0 * DD))[lane];
    }

    for (int p = beg; p < end; ++p) {
        unsigned qu = qn, vu = vn;
        if (p + 1 < end) {
            int s2 = col[p + 1];
            qn = ((const unsigned*)(QW + (size_t)s2 * DD))[lane];
            vn = ((const unsigned*)(V  + (size_t)s2 * DD))[lane];
        }
        float2 qf = bfp(qu);
        float part = qf.x * kf.x + qf.y * kf.y;
        part += __shfl_xor(part, 1);
        part += __shfl_xor(part, 2);
        part += __shfl_xor(part, 4);
        part += __shfl_xor(part, 8);
        part += __shfl_xor(part, 16);
        part += __shfl_xor(part, 32);
        float sc = part * 0.08838834764831845f;      // 1/sqrt(128)
        sc = sc > 0.f ? sc : 0.01f * sc;             // leaky_relu
        float nm = fmaxf(m, sc);
        float f  = __expf(m - nm);
        float pe = __expf(sc - nm);
        float2 vf = bfp(vu);
        den   = den * f + pe;
        acc.x = acc.x * f + pe * vf.x;
        acc.y = acc.y * f + pe * vf.y;
        m = nm;
    }

    float inv = den > 0.f ? 1.f / den : 0.f;
    ((float2*)(out + (size_t)wid * DD))[lane] = make_float2(acc.x * inv, acc.y * inv);
}

// ==================== host ====================
extern "C" void kernel_launch(void* const* d_in, const int* in_sizes, int n_in,
                              void* d_out, int out_size, void* d_ws, size_t ws_size,
                              hipStream_t stream)
{
    const float* x_a    = (const float*)d_in[0];
    const float* x_b    = (const float*)d_in[1];
    const int*   ei_ab  = (const int*)d_in[2];
    const int*   ei_ba  = (const int*)d_in[3];
    const float* qkv_w  = (const float*)d_in[4];
    const float* qkv_b  = (const float*)d_in[5];
    const float* edge_W = (const float*)d_in[6];
    float* out = (float*)d_out;

    const int N = in_sizes[0] / DD;    // 50000
    const int E = in_sizes[2] / 2;     // 600000
    const int nb = (N + 1023) / 1024;  // 49

    float* ws = (float*)d_ws;
    float* HA = ws;                          // layer-1 out a [N*D] f32
    float* HB = HA + (size_t)N * DD;         // layer-1 out b [N*D] f32
    float* WC  = HB + (size_t)N * DD;        // 4*128*128 f32
    float* BCq = WC + 4 * DD * DD;           // 4*128 f32
    float* B3  = BCq + 4 * DD;               // 4*384 f32
    ushort* W3P = (ushort*)(B3 + 4 * 384);   // 4*6144*8 bf16
    ushort* FQ = W3P + (size_t)4 * 6144 * 8; // q [N*D] bf16
    ushort* FV = FQ + (size_t)N * DD;        // v
    ushort* FK = FV + (size_t)N * DD;        // k
    int* ip      = (int*)(FK + (size_t)N * DD);
    int* deg2    = ip;                           // [2N]
    int* part    = deg2 + 2 * (size_t)N;         // [2*nb]
    int* offs_ab = part + 2 * nb;                // [N+1]
    int* offs_ba = offs_ab + (N + 1);            // [N+1]
    int* cur_ab  = offs_ba + (N + 1);            // [N]
    int* cur_ba  = cur_ab + N;                   // [N]
    int* col_ab  = cur_ba + N;                   // [E]
    int* col_ba  = col_ab + E;                   // [E]

    // ---- weight prep ----
    {
        dim3 g1(64, 4);
        combine_all<<<g1, 256, 0, stream>>>(qkv_w, qkv_b, edge_W, WC, BCq);
        dim3 g2(24, 4);
        pack_all<<<g2, 256, 0, stream>>>(qkv_w, qkv_b, WC, BCq, W3P, B3);
    }

    // ---- CSR (global atomics + hierarchical scan; reused by both layers) ----
    const int* s_ab = ei_ab;  const int* d_ab = ei_ab + E;
    const int* s_ba = ei_ba;  const int* d_ba = ei_ba + E;
    const int e_grid = (E + 255) / 256;
    {
        dim3 sg(nb, 2);
        zero_ints<<<(2 * N + 255) / 256, 256, 0, stream>>>(deg2, 2 * N);
        count_deg<<<e_grid, 256, 0, stream>>>(d_ab, d_ba, deg2, deg2 + N, E);
        scan_p1<<<sg, 256, 0, stream>>>(deg2, part, N, nb);
        scan_p2<<<1, 128, 0, stream>>>(part, nb, offs_ab, offs_ba, N);
        scan_p3<<<sg, 256, 0, stream>>>(deg2, part, offs_ab, offs_ba, cur_ab, cur_ba, N, nb);
        fill_csr<<<e_grid, 256, 0, stream>>>(s_ab, d_ab, s_ba, d_ba,
                                             cur_ab, cur_ba, col_ab, col_ba, E);
    }

    const dim3 gemm_grid((N + 63) / 64, 3);
    const int ag_grid = (N + 3) / 4;

    auto attend = [&](int z, const float* Xsrc, const float* Xdst, bool relu_in,
                      const int* offs, const int* col, float* outbuf) {
        const ushort* Bp = W3P + (size_t)z * 6144 * 8;
        const float* bz  = B3 + (size_t)z * 384;
        if (relu_in)
            gemm_mfma<true ><<<gemm_grid, 256, 0, stream>>>(Xsrc, Xdst, Bp, bz, FQ, N);
        else
            gemm_mfma<false><<<gemm_grid, 256, 0, stream>>>(Xsrc, Xdst, Bp, bz, FQ, N);
        attn_gather<<<ag_grid, 256, 0, stream>>>(FQ, FK, FV, offs, col, outbuf, N);
    };

    // layer 1
    attend(0, x_a, x_b, false, offs_ab, col_ab, HB);   // a->b, dst b
    attend(1, x_b, x_a, false, offs_ba, col_ba, HA);   // b->a, dst a
    // layer 2 (relu fused into GEMM A-stage)
    float* o_a = out;
    float* o_b = out + (size_t)N * DD;
    attend(2, HA, HB, true, offs_ab, col_ab, o_b);
    attend(3, HB, HA, true, offs_ba, col_ba, o_a);
}

// Round 7
// 485.790 us; speedup vs baseline: 2.0070x; 1.2213x over previous
//
#include <hip/hip_runtime.h>
#include <math.h>

#define DD 128

typedef __attribute__((ext_vector_type(8))) short bf16x8;  // 8 bf16 (4 VGPR)
typedef __attribute__((ext_vector_type(4))) float f32x4;   // 4 fp32 acc

__device__ __forceinline__ ushort f2bf(float f) {
    union { float f; unsigned u; } v; v.f = f;
    unsigned r = v.u + 0x7fff + ((v.u >> 16) & 1);   // RNE
    return (ushort)(r >> 16);
}

__device__ __forceinline__ float2 bfp(unsigned u) {
    union { unsigned x; float f; } a, b;
    a.x = u << 16;
    b.x = u & 0xffff0000u;
    return make_float2(a.f, b.f);
}

// ==================== weight prep (once per launch) ====================
__global__ __launch_bounds__(256) void combine_all(const float* __restrict__ qkv_w,
                                                   const float* __restrict__ qkv_b,
                                                   const float* __restrict__ edge_W,
                                                   float* __restrict__ WC,
                                                   float* __restrict__ BCq)
{
    const int z = blockIdx.y;          // (L<<1)|t
    const int L = z >> 1, t = z & 1;
    const float* wq = qkv_w + (((size_t)L * 2 + t) * 3 + 0) * DD * DD;
    const float* bq = qkv_b + (((size_t)L * 2 + t) * 3 + 0) * DD;
    const float* We = edge_W + ((size_t)L * 2 + t) * DD * DD;
    float* Wz = WC + (size_t)z * DD * DD;
    float* Bz = BCq + (size_t)z * DD;

    const int tid = threadIdx.x;
    const int i = blockIdx.x * 2 + (tid >> 7);
    const int j = tid & 127;
    float sum = 0.f;
    for (int k = 0; k < DD; ++k) sum = fmaf(wq[i * DD + k], We[k * DD + j], sum);
    Wz[i * DD + j] = sum;
    if (blockIdx.x == 0 && tid < DD) {
        float s2 = 0.f;
        for (int k = 0; k < DD; ++k) s2 = fmaf(bq[k], We[k * DD + j], s2);
        Bz[j] = s2;
    }
}

__global__ __launch_bounds__(256) void pack_all(const float* __restrict__ qkv_w,
                                                const float* __restrict__ qkv_b,
                                                const float* __restrict__ WC,
                                                const float* __restrict__ BCq,
                                                ushort* __restrict__ W3P,
                                                float* __restrict__ B3)
{
    const int z = blockIdx.y;
    const int L = z >> 1, t = z & 1;
    const int ci = blockIdx.x * 256 + threadIdx.x;     // 0..6143
    const int cb = ci >> 11;
    const int ct = (ci >> 8) & 7;
    const int ks = (ci >> 6) & 3;
    const int l  = ci & 63;
    const int c3 = cb * 128 + ct * 16 + (l & 15);
    const int k0 = ks * 32 + (l >> 4) * 8;

    const float* wv = qkv_w + (((size_t)L * 2 + t) * 3 + 2) * DD * DD;
    const float* wk = qkv_w + (((size_t)L * 2 + (t ^ 1)) * 3 + 1) * DD * DD;
    const float* src;
    int cc;
    if (c3 < 128)      { src = WC + (size_t)z * DD * DD; cc = c3; }
    else if (c3 < 256) { src = wv; cc = c3 - 128; }
    else               { src = wk; cc = c3 - 256; }

    ushort h[8];
    #pragma unroll
    for (int j = 0; j < 8; ++j) h[j] = f2bf(src[(size_t)(k0 + j) * DD + cc]);
    ushort* dst = W3P + (size_t)z * 6144 * 8 + (size_t)ci * 8;
    #pragma unroll
    for (int j = 0; j < 8; ++j) dst[j] = h[j];

    if (ci < 384) {
        float bv;
        if (ci < 128)      bv = BCq[(size_t)z * DD + ci];
        else if (ci < 256) bv = qkv_b[(((size_t)L * 2 + t) * 3 + 2) * DD + (ci - 128)];
        else               bv = qkv_b[(((size_t)L * 2 + (t ^ 1)) * 3 + 1) * DD + (ci - 256)];
        B3[(size_t)z * 384 + ci] = bv;
    }
}

// ==================== fused MFMA GEMM (bf16 out, QV interleaved) ====================
// grid (ceil(N/64), 3): y=0 -> q=Xsrc@Wc -> QV[...,0:128]
//                       y=1 -> v=Xsrc@wv -> QV[...,128:256]
//                       y=2 -> k=Xdst@wk -> FK
template<bool RELU_IN>
__global__ __launch_bounds__(256) void gemm_mfma(const float* __restrict__ Xsrc,
                                                 const float* __restrict__ Xdst,
                                                 const ushort* __restrict__ Bp,
                                                 const float* __restrict__ bias,
                                                 ushort* __restrict__ QV,
                                                 ushort* __restrict__ FK,
                                                 int N)
{
    const int by = blockIdx.y;
    const float* X = (by == 2) ? Xdst : Xsrc;
    const ushort* Bz = Bp + (size_t)by * 16384;
    const float* bz = bias + by * 128;
    ushort* outp   = (by == 2) ? FK : QV;
    const int stride = (by == 2) ? 128 : 256;
    const int off    = (by == 1) ? 128 : 0;

    __shared__ ushort As[1024 * 8];
    __shared__ ushort Bs[2048 * 8];

    const int tid  = threadIdx.x;
    const int row0 = blockIdx.x * 64;

    #pragma unroll
    for (int i = 0; i < 8; ++i) {
        int c = tid + i * 256;
        *(float4*)&Bs[(size_t)c * 8] = ((const float4*)Bz)[c];
    }

    {
        const int r = tid >> 2;
        const int q = tid & 3;
        const int grow = row0 + r;
        const bool ok = grow < N;
        const float* xr = X + (size_t)grow * DD;
        #pragma unroll
        for (int i = 0; i < 4; ++i) {
            const int k8 = q + i * 4;
            const int k  = k8 * 8;
            float4 v0 = make_float4(0.f,0.f,0.f,0.f), v1 = v0;
            if (ok) {
                v0 = *(const float4*)&xr[k];
                v1 = *(const float4*)&xr[k + 4];
                if (RELU_IN) {
                    v0.x=fmaxf(v0.x,0.f); v0.y=fmaxf(v0.y,0.f); v0.z=fmaxf(v0.z,0.f); v0.w=fmaxf(v0.w,0.f);
                    v1.x=fmaxf(v1.x,0.f); v1.y=fmaxf(v1.y,0.f); v1.z=fmaxf(v1.z,0.f); v1.w=fmaxf(v1.w,0.f);
                }
            }
            bf16x8 h;
            h[0]=(short)f2bf(v0.x); h[1]=(short)f2bf(v0.y); h[2]=(short)f2bf(v0.z); h[3]=(short)f2bf(v0.w);
            h[4]=(short)f2bf(v1.x); h[5]=(short)f2bf(v1.y); h[6]=(short)f2bf(v1.z); h[7]=(short)f2bf(v1.w);
            const int ks = k >> 5;
            const int l  = (r & 15) + 16 * (k8 & 3);
            const int c  = (r >> 4) * 256 + ks * 64 + l;
            *(bf16x8*)&As[(size_t)c * 8] = h;
        }
    }
    __syncthreads();

    const int wave = tid >> 6;
    const int lane = tid & 63;

    bf16x8 a[4];
    #pragma unroll
    for (int ks = 0; ks < 4; ++ks)
        a[ks] = *(const bf16x8*)&As[(size_t)(wave * 256 + ks * 64 + lane) * 8];

    f32x4 acc[8];
    #pragma unroll
    for (int ct = 0; ct < 8; ++ct) {
        acc[ct] = (f32x4){0.f, 0.f, 0.f, 0.f};
        #pragma unroll
        for (int ks = 0; ks < 4; ++ks) {
            bf16x8 b = *(const bf16x8*)&Bs[(size_t)((ct * 4 + ks) * 64 + lane) * 8];
            acc[ct] = __builtin_amdgcn_mfma_f32_16x16x32_bf16(a[ks], b, acc[ct], 0, 0, 0);
        }
    }

    const int rbase = row0 + wave * 16 + (lane >> 4) * 4;
    #pragma unroll
    for (int ct = 0; ct < 8; ++ct) {
        const int col = ct * 16 + (lane & 15);
        const float bv = bz[col];
        #pragma unroll
        for (int j = 0; j < 4; ++j) {
            const int rr = rbase + j;
            if (rr < N) outp[(size_t)rr * stride + off + col] = f2bf(acc[ct][j] + bv);
        }
    }
}

// ==================== CSR build (global atomics + hierarchical scan) ====================
__global__ __launch_bounds__(256) void zero_ints(int* __restrict__ p, int n)
{
    int i = blockIdx.x * 256 + threadIdx.x;
    if (i < n) p[i] = 0;
}

__global__ __launch_bounds__(256) void count_deg(const int* __restrict__ dab,
                                                 const int* __restrict__ dba,
                                                 int* __restrict__ degab,
                                                 int* __restrict__ degba, int nE)
{
    int e = blockIdx.x * 256 + threadIdx.x;
    if (e < nE) {
        atomicAdd(&degab[dab[e]], 1);
        atomicAdd(&degba[dba[e]], 1);
    }
}

__global__ __launch_bounds__(256) void scan_p1(const int* __restrict__ deg2,
                                               int* __restrict__ part, int N, int nb)
{
    const int t = blockIdx.y;
    const int* deg = deg2 + (size_t)t * N;
    const int idx = blockIdx.x * 1024 + threadIdx.x * 4;
    int s = 0;
    if (idx + 3 < N) {
        int4 v = *(const int4*)&deg[idx];
        s = v.x + v.y + v.z + v.w;
    } else {
        for (int j = 0; j < 4; ++j) if (idx + j < N) s += deg[idx + j];
    }
    __shared__ int red[256];
    red[threadIdx.x] = s;
    __syncthreads();
    for (int st = 128; st > 0; st >>= 1) {
        if (threadIdx.x < st) red[threadIdx.x] += red[threadIdx.x + st];
        __syncthreads();
    }
    if (threadIdx.x == 0) part[t * nb + blockIdx.x] = red[0];
}

__global__ __launch_bounds__(128) void scan_p2(int* __restrict__ part, int nb,
                                               int* __restrict__ offs0,
                                               int* __restrict__ offs1, int N)
{
    __shared__ int tmp[256];
    const int tid = threadIdx.x;
    for (int i = tid; i < 2 * nb; i += 128) tmp[i] = part[i];
    __syncthreads();
    if (tid < 2) {
        int run = 0;
        for (int i = 0; i < nb; ++i) { int v = tmp[tid * nb + i]; tmp[tid * nb + i] = run; run += v; }
        if (tid == 0) offs0[N] = run; else offs1[N] = run;
    }
    __syncthreads();
    for (int i = tid; i < 2 * nb; i += 128) part[i] = tmp[i];
}

__global__ __launch_bounds__(256) void scan_p3(const int* __restrict__ deg2,
                                               const int* __restrict__ part,
                                               int* __restrict__ offs0,
                                               int* __restrict__ offs1,
                                               int* __restrict__ cur0,
                                               int* __restrict__ cur1, int N, int nb)
{
    const int t = blockIdx.y;
    const int* deg = deg2 + (size_t)t * N;
    int* offs = t ? offs1 : offs0;
    int* cur  = t ? cur1 : cur0;
    const int idx = blockIdx.x * 1024 + threadIdx.x * 4;
    int4 v = make_int4(0, 0, 0, 0);
    if (idx + 3 < N) v = *(const int4*)&deg[idx];
    else {
        int tv[4] = {0,0,0,0};
        for (int j = 0; j < 4; ++j) if (idx + j < N) tv[j] = deg[idx + j];
        v.x = tv[0]; v.y = tv[1]; v.z = tv[2]; v.w = tv[3];
    }
    const int tsum = v.x + v.y + v.z + v.w;
    __shared__ int sc[256];
    sc[threadIdx.x] = tsum;
    __syncthreads();
    for (int off = 1; off < 256; off <<= 1) {
        int add = (threadIdx.x >= off) ? sc[threadIdx.x - off] : 0;
        __syncthreads();
        sc[threadIdx.x] += add;
        __syncthreads();
    }
    int o0 = part[t * nb + blockIdx.x] + sc[threadIdx.x] - tsum;
    int o1 = o0 + v.x, o2 = o1 + v.y, o3 = o2 + v.z;
    if (idx + 3 < N) {
        *(int4*)&offs[idx] = make_int4(o0, o1, o2, o3);
        *(int4*)&cur[idx]  = make_int4(o0, o1, o2, o3);
    } else {
        int oo[4] = {o0, o1, o2, o3};
        for (int j = 0; j < 4; ++j) if (idx + j < N) { offs[idx + j] = oo[j]; cur[idx + j] = oo[j]; }
    }
}

__global__ __launch_bounds__(256) void fill_csr(const int* __restrict__ sab,
                                                const int* __restrict__ dab,
                                                const int* __restrict__ sba,
                                                const int* __restrict__ dba,
                                                int* __restrict__ curab,
                                                int* __restrict__ curba,
                                                int* __restrict__ colab,
                                                int* __restrict__ colba, int nE)
{
    int e = blockIdx.x * 256 + threadIdx.x;
    if (e < nE) {
        int p = atomicAdd(&curab[dab[e]], 1);
        colab[p] = sab[e];
        int q = atomicAdd(&curba[dba[e]], 1);
        colba[q] = sba[e];
    }
}

// ==================== fused attention: 16 lanes/edge, 4 edges in flight ====================
// one wave per dst; group g (lanes 16g..16g+15) handles edges beg+g, beg+g+4, ...
// per-group online softmax; final cross-group merge via shfl_xor 16/32.
__global__ __launch_bounds__(256) void attn_gather(const ushort* __restrict__ QV,
                                                   const ushort* __restrict__ K,
                                                   const int* __restrict__ offs,
                                                   const int* __restrict__ col,
                                                   float* __restrict__ out, int n)
{
    const int wid  = (blockIdx.x * 256 + threadIdx.x) >> 6;
    const int lane = threadIdx.x & 63;
    if (wid >= n) return;
    const int li = lane & 15;
    const int g  = lane >> 4;

    const int beg = offs[wid], end = offs[wid + 1];

    uint4 ku = ((const uint4*)(K + (size_t)wid * DD))[li];
    float kf[8];
    {
        float2 t;
        t = bfp(ku.x); kf[0]=t.x; kf[1]=t.y;
        t = bfp(ku.y); kf[2]=t.x; kf[3]=t.y;
        t = bfp(ku.z); kf[4]=t.x; kf[5]=t.y;
        t = bfp(ku.w); kf[6]=t.x; kf[7]=t.y;
    }

    float m = -__builtin_inff();
    float den = 0.f;
    float acc[8] = {0.f,0.f,0.f,0.f,0.f,0.f,0.f,0.f};

    int p = beg + g;
    uint4 qn = make_uint4(0,0,0,0), vn = make_uint4(0,0,0,0);
    if (p < end) {
        const ushort* row = QV + (size_t)col[p] * 256;
        qn = ((const uint4*)row)[li];
        vn = ((const uint4*)(row + 128))[li];
    }

    while (p < end) {
        uint4 qu = qn, vu = vn;
        const int pn = p + 4;
        if (pn < end) {
            const ushort* row = QV + (size_t)col[pn] * 256;
            qn = ((const uint4*)row)[li];
            vn = ((const uint4*)(row + 128))[li];
        }
        float2 t;
        float d;
        t = bfp(qu.x); d  = t.x*kf[0] + t.y*kf[1];
        t = bfp(qu.y); d += t.x*kf[2] + t.y*kf[3];
        t = bfp(qu.z); d += t.x*kf[4] + t.y*kf[5];
        t = bfp(qu.w); d += t.x*kf[6] + t.y*kf[7];
        d += __shfl_xor(d, 1);
        d += __shfl_xor(d, 2);
        d += __shfl_xor(d, 4);
        d += __shfl_xor(d, 8);
        float sc = d * 0.08838834764831845f;      // 1/sqrt(128)
        sc = sc > 0.f ? sc : 0.01f * sc;          // leaky_relu
        float nm = fmaxf(m, sc);
        float f  = __expf(m - nm);                // first iter: exp(-inf)=0
        float pe = __expf(sc - nm);
        den = den * f + pe;
        float2 v0 = bfp(vu.x), v1 = bfp(vu.y), v2 = bfp(vu.z), v3 = bfp(vu.w);
        acc[0] = acc[0]*f + pe*v0.x;  acc[1] = acc[1]*f + pe*v0.y;
        acc[2] = acc[2]*f + pe*v1.x;  acc[3] = acc[3]*f + pe*v1.y;
        acc[4] = acc[4]*f + pe*v2.x;  acc[5] = acc[5]*f + pe*v2.y;
        acc[6] = acc[6]*f + pe*v3.x;  acc[7] = acc[7]*f + pe*v3.y;
        m = nm;
        p = pn;
    }

    // merge the 4 groups
    float m1 = fmaxf(m, __shfl_xor(m, 16));
    float m2 = fmaxf(m1, __shfl_xor(m1, 32));
    float f = (den > 0.f) ? __expf(m - m2) : 0.f;   // guard -inf - -inf
    den *= f;
    den += __shfl_xor(den, 16);
    den += __shfl_xor(den, 32);
    #pragma unroll
    for (int j = 0; j < 8; ++j) {
        acc[j] *= f;
        acc[j] += __shfl_xor(acc[j], 16);
        acc[j] += __shfl_xor(acc[j], 32);
    }
    if (g == 0) {
        const float inv = den > 0.f ? 1.f / den : 0.f;
        float* o = out + (size_t)wid * DD + li * 8;
        *(float4*)o       = make_float4(acc[0]*inv, acc[1]*inv, acc[2]*inv, acc[3]*inv);
        *(float4*)(o + 4) = make_float4(acc[4]*inv, acc[5]*inv, acc[6]*inv, acc[7]*inv);
    }
}

// ==================== host ====================
extern "C" void kernel_launch(void* const* d_in, const int* in_sizes, int n_in,
                              void* d_out, int out_size, void* d_ws, size_t ws_size,
                              hipStream_t stream)
{
    const float* x_a    = (const float*)d_in[0];
    const float* x_b    = (const float*)d_in[1];
    const int*   ei_ab  = (const int*)d_in[2];
    const int*   ei_ba  = (const int*)d_in[3];
    const float* qkv_w  = (const float*)d_in[4];
    const float* qkv_b  = (const float*)d_in[5];
    const float* edge_W = (const float*)d_in[6];
    float* out = (float*)d_out;

    const int N = in_sizes[0] / DD;    // 50000
    const int E = in_sizes[2] / 2;     // 600000
    const int nb = (N + 1023) / 1024;  // 49

    float* ws = (float*)d_ws;
    float* HA = ws;                          // layer-1 out a [N*D] f32
    float* HB = HA + (size_t)N * DD;         // layer-1 out b [N*D] f32
    float* WC  = HB + (size_t)N * DD;        // 4*128*128 f32
    float* BCq = WC + 4 * DD * DD;           // 4*128 f32
    float* B3  = BCq + 4 * DD;               // 4*384 f32
    ushort* W3P = (ushort*)(B3 + 4 * 384);   // 4*6144*8 bf16
    ushort* QV = W3P + (size_t)4 * 6144 * 8; // q|v interleaved [N*256] bf16
    ushort* FK = QV + (size_t)N * 256;       // k [N*128] bf16
    int* ip      = (int*)(FK + (size_t)N * DD);
    int* deg2    = ip;                           // [2N]
    int* part    = deg2 + 2 * (size_t)N;         // [2*nb]
    int* offs_ab = part + 2 * nb;                // [N+1]
    int* offs_ba = offs_ab + (N + 1);            // [N+1]
    int* cur_ab  = offs_ba + (N + 1);            // [N]
    int* cur_ba  = cur_ab + N;                   // [N]
    int* col_ab  = cur_ba + N;                   // [E]
    int* col_ba  = col_ab + E;                   // [E]

    // ---- weight prep ----
    {
        dim3 g1(64, 4);
        combine_all<<<g1, 256, 0, stream>>>(qkv_w, qkv_b, edge_W, WC, BCq);
        dim3 g2(24, 4);
        pack_all<<<g2, 256, 0, stream>>>(qkv_w, qkv_b, WC, BCq, W3P, B3);
    }

    // ---- CSR (global atomics + hierarchical scan; reused by both layers) ----
    const int* s_ab = ei_ab;  const int* d_ab = ei_ab + E;
    const int* s_ba = ei_ba;  const int* d_ba = ei_ba + E;
    const int e_grid = (E + 255) / 256;
    {
        dim3 sg(nb, 2);
        zero_ints<<<(2 * N + 255) / 256, 256, 0, stream>>>(deg2, 2 * N);
        count_deg<<<e_grid, 256, 0, stream>>>(d_ab, d_ba, deg2, deg2 + N, E);
        scan_p1<<<sg, 256, 0, stream>>>(deg2, part, N, nb);
        scan_p2<<<1, 128, 0, stream>>>(part, nb, offs_ab, offs_ba, N);
        scan_p3<<<sg, 256, 0, stream>>>(deg2, part, offs_ab, offs_ba, cur_ab, cur_ba, N, nb);
        fill_csr<<<e_grid, 256, 0, stream>>>(s_ab, d_ab, s_ba, d_ba,
                                             cur_ab, cur_ba, col_ab, col_ba, E);
    }

    const dim3 gemm_grid((N + 63) / 64, 3);
    const int ag_grid = (N + 3) / 4;

    auto attend = [&](int z, const float* Xsrc, const float* Xdst, bool relu_in,
                      const int* offs, const int* col, float* outbuf) {
        const ushort* Bp = W3P + (size_t)z * 6144 * 8;
        const float* bz  = B3 + (size_t)z * 384;
        if (relu_in)
            gemm_mfma<true ><<<gemm_grid, 256, 0, stream>>>(Xsrc, Xdst, Bp, bz, QV, FK, N);
        else
            gemm_mfma<false><<<gemm_grid, 256, 0, stream>>>(Xsrc, Xdst, Bp, bz, QV, FK, N);
        attn_gather<<<ag_grid, 256, 0, stream>>>(QV, FK, offs, col, outbuf, N);
    };

    // layer 1
    attend(0, x_a, x_b, false, offs_ab, col_ab, HB);   // a->b, dst b
    attend(1, x_b, x_a, false, offs_ba, col_ba, HA);   // b->a, dst a
    // layer 2 (relu fused into GEMM A-stage)
    float* o_a = out;
    float* o_b = out + (size_t)N * DD;
    attend(2, HA, HB, true, offs_ab, col_ab, o_b);
    attend(3, HB, HA, true, offs_ba, col_ba, o_a);
}

// Round 8
// 392.420 us; speedup vs baseline: 2.4846x; 1.2379x over previous
//
#include <hip/hip_runtime.h>
#include <math.h>

#define DD 128
#define CHUNK 8192
#define CAP 5120

typedef __attribute__((ext_vector_type(8))) short bf16x8;  // 8 bf16 (4 VGPR)
typedef __attribute__((ext_vector_type(4))) float f32x4;   // 4 fp32 acc

__device__ __forceinline__ ushort f2bf(float f) {
    union { float f; unsigned u; } v; v.f = f;
    unsigned r = v.u + 0x7fff + ((v.u >> 16) & 1);   // RNE
    return (ushort)(r >> 16);
}

__device__ __forceinline__ float2 bfp(unsigned u) {
    union { unsigned x; float f; } a, b;
    a.x = u << 16;
    b.x = u & 0xffff0000u;
    return make_float2(a.f, b.f);
}

// ==================== weight prep (once per launch) ====================
__global__ __launch_bounds__(256) void combine_all(const float* __restrict__ qkv_w,
                                                   const float* __restrict__ qkv_b,
                                                   const float* __restrict__ edge_W,
                                                   float* __restrict__ WC,
                                                   float* __restrict__ BCq)
{
    const int z = blockIdx.y;          // (L<<1)|t
    const int L = z >> 1, t = z & 1;
    const float* wq = qkv_w + (((size_t)L * 2 + t) * 3 + 0) * DD * DD;
    const float* bq = qkv_b + (((size_t)L * 2 + t) * 3 + 0) * DD;
    const float* We = edge_W + ((size_t)L * 2 + t) * DD * DD;
    float* Wz = WC + (size_t)z * DD * DD;
    float* Bz = BCq + (size_t)z * DD;

    const int tid = threadIdx.x;
    const int i = blockIdx.x * 2 + (tid >> 7);
    const int j = tid & 127;
    float sum = 0.f;
    for (int k = 0; k < DD; ++k) sum = fmaf(wq[i * DD + k], We[k * DD + j], sum);
    Wz[i * DD + j] = sum;
    if (blockIdx.x == 0 && tid < DD) {
        float s2 = 0.f;
        for (int k = 0; k < DD; ++k) s2 = fmaf(bq[k], We[k * DD + j], s2);
        Bz[j] = s2;
    }
}

__global__ __launch_bounds__(256) void pack_all(const float* __restrict__ qkv_w,
                                                const float* __restrict__ qkv_b,
                                                const float* __restrict__ WC,
                                                const float* __restrict__ BCq,
                                                ushort* __restrict__ W3P,
                                                float* __restrict__ B3)
{
    const int z = blockIdx.y;
    const int L = z >> 1, t = z & 1;
    const int ci = blockIdx.x * 256 + threadIdx.x;     // 0..6143
    const int cb = ci >> 11;
    const int ct = (ci >> 8) & 7;
    const int ks = (ci >> 6) & 3;
    const int l  = ci & 63;
    const int c3 = cb * 128 + ct * 16 + (l & 15);
    const int k0 = ks * 32 + (l >> 4) * 8;

    const float* wv = qkv_w + (((size_t)L * 2 + t) * 3 + 2) * DD * DD;
    const float* wk = qkv_w + (((size_t)L * 2 + (t ^ 1)) * 3 + 1) * DD * DD;
    const float* src;
    int cc;
    if (c3 < 128)      { src = WC + (size_t)z * DD * DD; cc = c3; }
    else if (c3 < 256) { src = wv; cc = c3 - 128; }
    else               { src = wk; cc = c3 - 256; }

    ushort h[8];
    #pragma unroll
    for (int j = 0; j < 8; ++j) h[j] = f2bf(src[(size_t)(k0 + j) * DD + cc]);
    ushort* dst = W3P + (size_t)z * 6144 * 8 + (size_t)ci * 8;
    #pragma unroll
    for (int j = 0; j < 8; ++j) dst[j] = h[j];

    if (ci < 384) {
        float bv;
        if (ci < 128)      bv = BCq[(size_t)z * DD + ci];
        else if (ci < 256) bv = qkv_b[(((size_t)L * 2 + t) * 3 + 2) * DD + (ci - 128)];
        else               bv = qkv_b[(((size_t)L * 2 + (t ^ 1)) * 3 + 1) * DD + (ci - 256)];
        B3[(size_t)z * 384 + ci] = bv;
    }
}

// ==================== fused MFMA GEMM (bf16 out, QV interleaved) ====================
template<bool RELU_IN>
__global__ __launch_bounds__(256) void gemm_mfma(const float* __restrict__ Xsrc,
                                                 const float* __restrict__ Xdst,
                                                 const ushort* __restrict__ Bp,
                                                 const float* __restrict__ bias,
                                                 ushort* __restrict__ QV,
                                                 ushort* __restrict__ FK,
                                                 int N)
{
    const int by = blockIdx.y;
    const float* X = (by == 2) ? Xdst : Xsrc;
    const ushort* Bz = Bp + (size_t)by * 16384;
    const float* bz = bias + by * 128;
    ushort* outp   = (by == 2) ? FK : QV;
    const int stride = (by == 2) ? 128 : 256;
    const int off    = (by == 1) ? 128 : 0;

    __shared__ ushort As[1024 * 8];
    __shared__ ushort Bs[2048 * 8];

    const int tid  = threadIdx.x;
    const int row0 = blockIdx.x * 64;

    #pragma unroll
    for (int i = 0; i < 8; ++i) {
        int c = tid + i * 256;
        *(float4*)&Bs[(size_t)c * 8] = ((const float4*)Bz)[c];
    }

    {
        const int r = tid >> 2;
        const int q = tid & 3;
        const int grow = row0 + r;
        const bool ok = grow < N;
        const float* xr = X + (size_t)grow * DD;
        #pragma unroll
        for (int i = 0; i < 4; ++i) {
            const int k8 = q + i * 4;
            const int k  = k8 * 8;
            float4 v0 = make_float4(0.f,0.f,0.f,0.f), v1 = v0;
            if (ok) {
                v0 = *(const float4*)&xr[k];
                v1 = *(const float4*)&xr[k + 4];
                if (RELU_IN) {
                    v0.x=fmaxf(v0.x,0.f); v0.y=fmaxf(v0.y,0.f); v0.z=fmaxf(v0.z,0.f); v0.w=fmaxf(v0.w,0.f);
                    v1.x=fmaxf(v1.x,0.f); v1.y=fmaxf(v1.y,0.f); v1.z=fmaxf(v1.z,0.f); v1.w=fmaxf(v1.w,0.f);
                }
            }
            bf16x8 h;
            h[0]=(short)f2bf(v0.x); h[1]=(short)f2bf(v0.y); h[2]=(short)f2bf(v0.z); h[3]=(short)f2bf(v0.w);
            h[4]=(short)f2bf(v1.x); h[5]=(short)f2bf(v1.y); h[6]=(short)f2bf(v1.z); h[7]=(short)f2bf(v1.w);
            const int ks = k >> 5;
            const int l  = (r & 15) + 16 * (k8 & 3);
            const int c  = (r >> 4) * 256 + ks * 64 + l;
            *(bf16x8*)&As[(size_t)c * 8] = h;
        }
    }
    __syncthreads();

    const int wave = tid >> 6;
    const int lane = tid & 63;

    bf16x8 a[4];
    #pragma unroll
    for (int ks = 0; ks < 4; ++ks)
        a[ks] = *(const bf16x8*)&As[(size_t)(wave * 256 + ks * 64 + lane) * 8];

    f32x4 acc[8];
    #pragma unroll
    for (int ct = 0; ct < 8; ++ct) {
        acc[ct] = (f32x4){0.f, 0.f, 0.f, 0.f};
        #pragma unroll
        for (int ks = 0; ks < 4; ++ks) {
            bf16x8 b = *(const bf16x8*)&Bs[(size_t)((ct * 4 + ks) * 64 + lane) * 8];
            acc[ct] = __builtin_amdgcn_mfma_f32_16x16x32_bf16(a[ks], b, acc[ct], 0, 0, 0);
        }
    }

    const int rbase = row0 + wave * 16 + (lane >> 4) * 4;
    #pragma unroll
    for (int ct = 0; ct < 8; ++ct) {
        const int col = ct * 16 + (lane & 15);
        const float bv = bz[col];
        #pragma unroll
        for (int j = 0; j < 4; ++j) {
            const int rr = rbase + j;
            if (rr < N) outp[(size_t)rr * stride + off + col] = f2bf(acc[ct][j] + bv);
        }
    }
}

// ==================== CSR build: two-level bucket counting sort ====================
// bucket = dst >> 8 (width 256 nodes); packed edge u32 = (b<<24)|(dl<<16)|src
__global__ __launch_bounds__(256) void zero_ints(int* __restrict__ p, int n)
{
    int i = blockIdx.x * 256 + threadIdx.x;
    if (i < n) p[i] = 0;
}

__global__ __launch_bounds__(256) void bkt_hist(const int* __restrict__ dst0,
                                                const int* __restrict__ dst1,
                                                int* __restrict__ bcnt, int nE)
{
    const int t = blockIdx.y;
    const int* dst = t ? dst1 : dst0;
    __shared__ int h[256];
    h[threadIdx.x] = 0;
    __syncthreads();
    for (int e = blockIdx.x * 256 + threadIdx.x; e < nE; e += gridDim.x * 256)
        atomicAdd(&h[dst[e] >> 8], 1);
    __syncthreads();
    if (h[threadIdx.x]) atomicAdd(&bcnt[t * 256 + threadIdx.x], h[threadIdx.x]);
}

__global__ __launch_bounds__(64) void bkt_scan(const int* __restrict__ bcnt,
                                               int* __restrict__ bbase,
                                               int* __restrict__ bcur,
                                               int* __restrict__ offs0,
                                               int* __restrict__ offs1, int N, int nE)
{
    if (threadIdx.x < 2) {
        int t = threadIdx.x;
        int run = 0;
        for (int i = 0; i < 256; ++i) {
            int v = bcnt[t * 256 + i];
            bbase[t * 256 + i] = run;
            bcur[t * 256 + i] = run;
            run += v;
        }
        if (t == 0) offs0[N] = nE; else offs1[N] = nE;
    }
}

// counting-sort an 8192-edge chunk in LDS, copy out contiguous bucket segments
__global__ __launch_bounds__(256) void bkt_part(const int* __restrict__ src0,
                                                const int* __restrict__ dst0,
                                                const int* __restrict__ src1,
                                                const int* __restrict__ dst1,
                                                int* __restrict__ bcur,
                                                unsigned* __restrict__ stage0,
                                                unsigned* __restrict__ stage1,
                                                int nE, int nbkt)
{
    const int t = blockIdx.y;
    const int* src = t ? src1 : src0;
    const int* dst = t ? dst1 : dst0;
    unsigned* stage = t ? stage1 : stage0;
    int* bc = bcur + t * 256;

    __shared__ unsigned ebuf[CHUNK];                   // 32 KB
    __shared__ int cnt[256], loff[256], cur[256], resv[256];

    const int tid  = threadIdx.x;
    const int e0   = blockIdx.x * CHUNK;
    const int ecnt = min(CHUNK, nE - e0);

    cnt[tid] = 0;
    __syncthreads();

    unsigned pk[CHUNK / 256];
    #pragma unroll
    for (int i = 0; i < CHUNK / 256; ++i) {
        const int le = i * 256 + tid;
        unsigned p = 0xFFFFFFFFu;
        if (le < ecnt) {
            int d = dst[e0 + le], s = src[e0 + le];
            p = ((unsigned)(d >> 8) << 24) | ((unsigned)(d & 255) << 16) | (unsigned)s;
            atomicAdd(&cnt[d >> 8], 1);
        }
        pk[i] = p;
    }
    __syncthreads();

    // exclusive scan of cnt
    int v = cnt[tid];
    loff[tid] = v;
    __syncthreads();
    for (int off = 1; off < 256; off <<= 1) {
        int a = (tid >= off) ? loff[tid - off] : 0;
        __syncthreads();
        loff[tid] += a;
        __syncthreads();
    }
    int excl = loff[tid] - v;
    __syncthreads();
    loff[tid] = excl;
    cur[tid]  = excl;
    __syncthreads();

    // scatter into LDS
    #pragma unroll
    for (int i = 0; i < CHUNK / 256; ++i) {
        unsigned p = pk[i];
        if (p != 0xFFFFFFFFu) {
            int b = p >> 24;
            int pos = atomicAdd(&cur[b], 1);
            ebuf[pos] = p;
        }
    }
    __syncthreads();

    // reserve global segments (one atomic per non-empty bucket)
    if (tid < nbkt && cnt[tid] > 0) resv[tid] = atomicAdd(&bc[tid], cnt[tid]);
    __syncthreads();

    // copy out: wave w handles buckets w, w+4, ...
    const int wv = tid >> 6, ln = tid & 63;
    for (int b = wv; b < nbkt; b += 4) {
        const int c = cnt[b];
        if (c == 0) continue;
        const int lo = loff[b];
        const int rb = resv[b];
        for (int i = ln; i < c; i += 64) stage[rb + i] = ebuf[lo + i];
    }
}

// one block per bucket: per-dst count+scan+scatter in LDS; coalesced offs/col writes
__global__ __launch_bounds__(256) void bkt_fill(const unsigned* __restrict__ stage0,
                                                const unsigned* __restrict__ stage1,
                                                const int* __restrict__ bcnt,
                                                const int* __restrict__ bbase,
                                                int* __restrict__ offs0,
                                                int* __restrict__ offs1,
                                                int* __restrict__ col0,
                                                int* __restrict__ col1, int N)
{
    const int b = blockIdx.x, t = blockIdx.y;
    const unsigned* stage = t ? stage1 : stage0;
    int* offs = t ? offs1 : offs0;
    int* col  = t ? col1 : col0;
    const int base = bbase[t * 256 + b];
    int cb = bcnt[t * 256 + b];
    if (cb > CAP) cb = CAP;   // statistically impossible; guard LDS

    __shared__ unsigned ebuf[CAP];   // 20 KB
    __shared__ int colbuf[CAP];      // 20 KB
    __shared__ int dcnt[256], doff[256], dcur[256];

    const int tid = threadIdx.x;
    dcnt[tid] = 0;
    __syncthreads();

    for (int i = tid; i < cb; i += 256) {
        unsigned p = stage[base + i];
        ebuf[i] = p;
        atomicAdd(&dcnt[(p >> 16) & 255], 1);
    }
    __syncthreads();

    int v = dcnt[tid];
    doff[tid] = v;
    __syncthreads();
    for (int off = 1; off < 256; off <<= 1) {
        int a = (tid >= off) ? doff[tid - off] : 0;
        __syncthreads();
        doff[tid] += a;
        __syncthreads();
    }
    int excl = doff[tid] - v;
    dcur[tid] = excl;
    const int node = (b << 8) + tid;
    if (node < N) offs[node] = base + excl;
    __syncthreads();

    for (int i = tid; i < cb; i += 256) {
        unsigned p = ebuf[i];
        int pos = atomicAdd(&dcur[(p >> 16) & 255], 1);
        colbuf[pos] = (int)(p & 0xFFFFu);
    }
    __syncthreads();

    for (int i = tid; i < cb; i += 256) col[base + i] = colbuf[i];
}

// ==================== fused attention: 16 lanes/edge, 4 edges in flight ====================
__global__ __launch_bounds__(256) void attn_gather(const ushort* __restrict__ QV,
                                                   const ushort* __restrict__ K,
                                                   const int* __restrict__ offs,
                                                   const int* __restrict__ col,
                                                   float* __restrict__ out, int n)
{
    const int wid  = (blockIdx.x * 256 + threadIdx.x) >> 6;
    const int lane = threadIdx.x & 63;
    if (wid >= n) return;
    const int li = lane & 15;
    const int g  = lane >> 4;

    const int beg = offs[wid], end = offs[wid + 1];

    uint4 ku = ((const uint4*)(K + (size_t)wid * DD))[li];
    float kf[8];
    {
        float2 t;
        t = bfp(ku.x); kf[0]=t.x; kf[1]=t.y;
        t = bfp(ku.y); kf[2]=t.x; kf[3]=t.y;
        t = bfp(ku.z); kf[4]=t.x; kf[5]=t.y;
        t = bfp(ku.w); kf[6]=t.x; kf[7]=t.y;
    }

    float m = -__builtin_inff();
    float den = 0.f;
    float acc[8] = {0.f,0.f,0.f,0.f,0.f,0.f,0.f,0.f};

    int p = beg + g;
    uint4 qn = make_uint4(0,0,0,0), vn = make_uint4(0,0,0,0);
    if (p < end) {
        const ushort* row = QV + (size_t)col[p] * 256;
        qn = ((const uint4*)row)[li];
        vn = ((const uint4*)(row + 128))[li];
    }

    while (p < end) {
        uint4 qu = qn, vu = vn;
        const int pn = p + 4;
        if (pn < end) {
            const ushort* row = QV + (size_t)col[pn] * 256;
            qn = ((const uint4*)row)[li];
            vn = ((const uint4*)(row + 128))[li];
        }
        float2 t;
        float d;
        t = bfp(qu.x); d  = t.x*kf[0] + t.y*kf[1];
        t = bfp(qu.y); d += t.x*kf[2] + t.y*kf[3];
        t = bfp(qu.z); d += t.x*kf[4] + t.y*kf[5];
        t = bfp(qu.w); d += t.x*kf[6] + t.y*kf[7];
        d += __shfl_xor(d, 1);
        d += __shfl_xor(d, 2);
        d += __shfl_xor(d, 4);
        d += __shfl_xor(d, 8);
        float sc = d * 0.08838834764831845f;      // 1/sqrt(128)
        sc = sc > 0.f ? sc : 0.01f * sc;          // leaky_relu
        float nm = fmaxf(m, sc);
        float f  = __expf(m - nm);                // first iter: exp(-inf)=0
        float pe = __expf(sc - nm);
        den = den * f + pe;
        float2 v0 = bfp(vu.x), v1 = bfp(vu.y), v2 = bfp(vu.z), v3 = bfp(vu.w);
        acc[0] = acc[0]*f + pe*v0.x;  acc[1] = acc[1]*f + pe*v0.y;
        acc[2] = acc[2]*f + pe*v1.x;  acc[3] = acc[3]*f + pe*v1.y;
        acc[4] = acc[4]*f + pe*v2.x;  acc[5] = acc[5]*f + pe*v2.y;
        acc[6] = acc[6]*f + pe*v3.x;  acc[7] = acc[7]*f + pe*v3.y;
        m = nm;
        p = pn;
    }

    // merge the 4 groups
    float m1 = fmaxf(m, __shfl_xor(m, 16));
    float m2 = fmaxf(m1, __shfl_xor(m1, 32));
    float f = (den > 0.f) ? __expf(m - m2) : 0.f;   // guard -inf - -inf
    den *= f;
    den += __shfl_xor(den, 16);
    den += __shfl_xor(den, 32);
    #pragma unroll
    for (int j = 0; j < 8; ++j) {
        acc[j] *= f;
        acc[j] += __shfl_xor(acc[j], 16);
        acc[j] += __shfl_xor(acc[j], 32);
    }
    if (g == 0) {
        const float inv = den > 0.f ? 1.f / den : 0.f;
        float* o = out + (size_t)wid * DD + li * 8;
        *(float4*)o       = make_float4(acc[0]*inv, acc[1]*inv, acc[2]*inv, acc[3]*inv);
        *(float4*)(o + 4) = make_float4(acc[4]*inv, acc[5]*inv, acc[6]*inv, acc[7]*inv);
    }
}

// ==================== host ====================
extern "C" void kernel_launch(void* const* d_in, const int* in_sizes, int n_in,
                              void* d_out, int out_size, void* d_ws, size_t ws_size,
                              hipStream_t stream)
{
    const float* x_a    = (const float*)d_in[0];
    const float* x_b    = (const float*)d_in[1];
    const int*   ei_ab  = (const int*)d_in[2];
    const int*   ei_ba  = (const int*)d_in[3];
    const float* qkv_w  = (const float*)d_in[4];
    const float* qkv_b  = (const float*)d_in[5];
    const float* edge_W = (const float*)d_in[6];
    float* out = (float*)d_out;

    const int N = in_sizes[0] / DD;    // 50000
    const int E = in_sizes[2] / 2;     // 600000
    const int nbkt = (N + 255) >> 8;   // 196

    float* ws = (float*)d_ws;
    float* HA = ws;                          // layer-1 out a [N*D] f32
    float* HB = HA + (size_t)N * DD;         // layer-1 out b [N*D] f32
    float* WC  = HB + (size_t)N * DD;        // 4*128*128 f32
    float* BCq = WC + 4 * DD * DD;           // 4*128 f32
    float* B3  = BCq + 4 * DD;               // 4*384 f32
    ushort* W3P = (ushort*)(B3 + 4 * 384);   // 4*6144*8 bf16
    ushort* QV = W3P + (size_t)4 * 6144 * 8; // q|v interleaved [N*256] bf16
    ushort* FK = QV + (size_t)N * 256;       // k [N*128] bf16
    int* ip      = (int*)(FK + (size_t)N * DD);
    int* bcnt    = ip;                           // [512]
    int* bbase   = bcnt + 512;                   // [512]
    int* bcur    = bbase + 512;                  // [512]
    int* offs_ab = bcur + 512;                   // [N+1]
    int* offs_ba = offs_ab + (N + 1);            // [N+1]
    int* col_ab  = offs_ba + (N + 1);            // [E]
    int* col_ba  = col_ab + E;                   // [E]
    unsigned* stage0 = (unsigned*)(col_ba + E);  // [E]
    unsigned* stage1 = stage0 + E;               // [E]

    // ---- weight prep ----
    {
        dim3 g1(64, 4);
        combine_all<<<g1, 256, 0, stream>>>(qkv_w, qkv_b, edge_W, WC, BCq);
        dim3 g2(24, 4);
        pack_all<<<g2, 256, 0, stream>>>(qkv_w, qkv_b, WC, BCq, W3P, B3);
    }

    // ---- CSR via two-level bucket sort (reused by both layers) ----
    const int* s_ab = ei_ab;  const int* d_ab = ei_ab + E;
    const int* s_ba = ei_ba;  const int* d_ba = ei_ba + E;
    {
        zero_ints<<<2, 256, 0, stream>>>(bcnt, 512);
        dim3 hg(128, 2);
        bkt_hist<<<hg, 256, 0, stream>>>(d_ab, d_ba, bcnt, E);
        bkt_scan<<<1, 64, 0, stream>>>(bcnt, bbase, bcur, offs_ab, offs_ba, N, E);
        dim3 pg((E + CHUNK - 1) / CHUNK, 2);
        bkt_part<<<pg, 256, 0, stream>>>(s_ab, d_ab, s_ba, d_ba, bcur,
                                         stage0, stage1, E, nbkt);
        dim3 fg(nbkt, 2);
        bkt_fill<<<fg, 256, 0, stream>>>(stage0, stage1, bcnt, bbase,
                                         offs_ab, offs_ba, col_ab, col_ba, N);
    }

    const dim3 gemm_grid((N + 63) / 64, 3);
    const int ag_grid = (N + 3) / 4;

    auto attend = [&](int z, const float* Xsrc, const float* Xdst, bool relu_in,
                      const int* offs, const int* col, float* outbuf) {
        const ushort* Bp = W3P + (size_t)z * 6144 * 8;
        const float* bz  = B3 + (size_t)z * 384;
        if (relu_in)
            gemm_mfma<true ><<<gemm_grid, 256, 0, stream>>>(Xsrc, Xdst, Bp, bz, QV, FK, N);
        else
            gemm_mfma<false><<<gemm_grid, 256, 0, stream>>>(Xsrc, Xdst, Bp, bz, QV, FK, N);
        attn_gather<<<ag_grid, 256, 0, stream>>>(QV, FK, offs, col, outbuf, N);
    };

    // layer 1
    attend(0, x_a, x_b, false, offs_ab, col_ab, HB);   // a->b, dst b
    attend(1, x_b, x_a, false, offs_ba, col_ba, HA);   // b->a, dst a
    // layer 2 (relu fused into GEMM A-stage)
    float* o_a = out;
    float* o_b = out + (size_t)N * DD;
    attend(2, HA, HB, true, offs_ab, col_ab, o_b);
    attend(3, HB, HA, true, offs_ba, col_ba, o_a);
}

// Round 9
// 381.076 us; speedup vs baseline: 2.5585x; 1.0298x over previous
//
#include <hip/hip_runtime.h>
#include <math.h>

#define DD 128
#define CHUNK 8192
#define CAP 5120

typedef __attribute__((ext_vector_type(8))) short bf16x8;  // 8 bf16 (4 VGPR)
typedef __attribute__((ext_vector_type(4))) float f32x4;   // 4 fp32 acc

__device__ __forceinline__ ushort f2bf(float f) {
    union { float f; unsigned u; } v; v.f = f;
    unsigned r = v.u + 0x7fff + ((v.u >> 16) & 1);   // RNE
    return (ushort)(r >> 16);
}

__device__ __forceinline__ float2 bfp(unsigned u) {
    union { unsigned x; float f; } a, b;
    a.x = u << 16;
    b.x = u & 0xffff0000u;
    return make_float2(a.f, b.f);
}

// ==================== f32 -> bf16 bulk convert ====================
__global__ __launch_bounds__(256) void xcvt(const float* __restrict__ in,
                                            ushort* __restrict__ out, int n8)
{
    for (int i = blockIdx.x * 256 + threadIdx.x; i < n8; i += gridDim.x * 256) {
        float4 v0 = ((const float4*)in)[(size_t)i * 2];
        float4 v1 = ((const float4*)in)[(size_t)i * 2 + 1];
        bf16x8 h;
        h[0]=(short)f2bf(v0.x); h[1]=(short)f2bf(v0.y); h[2]=(short)f2bf(v0.z); h[3]=(short)f2bf(v0.w);
        h[4]=(short)f2bf(v1.x); h[5]=(short)f2bf(v1.y); h[6]=(short)f2bf(v1.z); h[7]=(short)f2bf(v1.w);
        *(bf16x8*)&out[(size_t)i * 8] = h;
    }
}

// ==================== weight prep (once per launch) ====================
__global__ __launch_bounds__(256) void combine_all(const float* __restrict__ qkv_w,
                                                   const float* __restrict__ qkv_b,
                                                   const float* __restrict__ edge_W,
                                                   float* __restrict__ WC,
                                                   float* __restrict__ BCq)
{
    const int z = blockIdx.y;          // (L<<1)|t
    const int L = z >> 1, t = z & 1;
    const float* wq = qkv_w + (((size_t)L * 2 + t) * 3 + 0) * DD * DD;
    const float* bq = qkv_b + (((size_t)L * 2 + t) * 3 + 0) * DD;
    const float* We = edge_W + ((size_t)L * 2 + t) * DD * DD;
    float* Wz = WC + (size_t)z * DD * DD;
    float* Bz = BCq + (size_t)z * DD;

    const int tid = threadIdx.x;
    const int i = blockIdx.x * 2 + (tid >> 7);
    const int j = tid & 127;
    float sum = 0.f;
    for (int k = 0; k < DD; ++k) sum = fmaf(wq[i * DD + k], We[k * DD + j], sum);
    Wz[i * DD + j] = sum;
    if (blockIdx.x == 0 && tid < DD) {
        float s2 = 0.f;
        for (int k = 0; k < DD; ++k) s2 = fmaf(bq[k], We[k * DD + j], s2);
        Bz[j] = s2;
    }
}

__global__ __launch_bounds__(256) void pack_all(const float* __restrict__ qkv_w,
                                                const float* __restrict__ qkv_b,
                                                const float* __restrict__ WC,
                                                const float* __restrict__ BCq,
                                                ushort* __restrict__ W3P,
                                                float* __restrict__ B3)
{
    const int z = blockIdx.y;
    const int L = z >> 1, t = z & 1;
    const int ci = blockIdx.x * 256 + threadIdx.x;     // 0..6143
    const int cb = ci >> 11;
    const int ct = (ci >> 8) & 7;
    const int ks = (ci >> 6) & 3;
    const int l  = ci & 63;
    const int c3 = cb * 128 + ct * 16 + (l & 15);
    const int k0 = ks * 32 + (l >> 4) * 8;

    const float* wv = qkv_w + (((size_t)L * 2 + t) * 3 + 2) * DD * DD;
    const float* wk = qkv_w + (((size_t)L * 2 + (t ^ 1)) * 3 + 1) * DD * DD;
    const float* src;
    int cc;
    if (c3 < 128)      { src = WC + (size_t)z * DD * DD; cc = c3; }
    else if (c3 < 256) { src = wv; cc = c3 - 128; }
    else               { src = wk; cc = c3 - 256; }

    ushort h[8];
    #pragma unroll
    for (int j = 0; j < 8; ++j) h[j] = f2bf(src[(size_t)(k0 + j) * DD + cc]);
    ushort* dst = W3P + (size_t)z * 6144 * 8 + (size_t)ci * 8;
    #pragma unroll
    for (int j = 0; j < 8; ++j) dst[j] = h[j];

    if (ci < 384) {
        float bv;
        if (ci < 128)      bv = BCq[(size_t)z * DD + ci];
        else if (ci < 256) bv = qkv_b[(((size_t)L * 2 + t) * 3 + 2) * DD + (ci - 128)];
        else               bv = qkv_b[(((size_t)L * 2 + (t ^ 1)) * 3 + 1) * DD + (ci - 256)];
        B3[(size_t)z * 384 + ci] = bv;
    }
}

// ==================== LDS-free MFMA GEMM (bf16 in, bf16 out, QV interleaved) ====================
// grid (ceil(N/64), 3): y=0 -> q=Xsrc@Wc -> QV[:,0:128]; y=1 -> v=Xsrc@wv -> QV[:,128:256];
//                       y=2 -> k=Xdst@wk -> FK.  A-frags and B-frags loaded straight from global.
template<bool RELU_IN>
__global__ __launch_bounds__(256, 4) void gemm_mfma(const ushort* __restrict__ Xsrc,
                                                    const ushort* __restrict__ Xdst,
                                                    const ushort* __restrict__ Bp,
                                                    const float* __restrict__ bias,
                                                    ushort* __restrict__ QV,
                                                    ushort* __restrict__ FK,
                                                    int N)
{
    const int by = blockIdx.y;
    const ushort* X = (by == 2) ? Xdst : Xsrc;
    const ushort* Bz = Bp + (size_t)by * 16384;
    const float* bz = bias + by * 128;
    ushort* outp   = (by == 2) ? FK : QV;
    const int stride = (by == 2) ? 128 : 256;
    const int off    = (by == 1) ? 128 : 0;

    const int wave = threadIdx.x >> 6;
    const int lane = threadIdx.x & 63;
    const int row0 = blockIdx.x * 64 + wave * 16;

    // A fragments: lane holds A[arow][(ks*4 + (lane>>4))*8 + j]
    // per instruction: 64 lanes cover 16 rows x 64 contiguous bytes (full lines)
    const int arow = row0 + (lane & 15);
    const bool aok = arow < N;
    const ushort* xr = X + (size_t)arow * DD + (lane >> 4) * 8;

    bf16x8 a[4];
    #pragma unroll
    for (int ks = 0; ks < 4; ++ks) {
        bf16x8 h = (bf16x8){0,0,0,0,0,0,0,0};
        if (aok) h = *(const bf16x8*)&xr[ks * 32];
        if (RELU_IN) {
            #pragma unroll
            for (int j = 0; j < 8; ++j)
                h[j] = (short)(((ushort)h[j] & 0x8000u) ? 0 : (ushort)h[j]);
        }
        a[ks] = h;
    }

    f32x4 acc[8];
    #pragma unroll
    for (int ct = 0; ct < 8; ++ct) {
        acc[ct] = (f32x4){0.f, 0.f, 0.f, 0.f};
        #pragma unroll
        for (int ks = 0; ks < 4; ++ks) {
            bf16x8 b = *(const bf16x8*)&Bz[(size_t)((ct * 4 + ks) * 64 + lane) * 8];
            acc[ct] = __builtin_amdgcn_mfma_f32_16x16x32_bf16(a[ks], b, acc[ct], 0, 0, 0);
        }
    }

    // store bf16: C/D map col=lane&15, row=(lane>>4)*4+reg
    const int rbase = row0 + (lane >> 4) * 4;
    #pragma unroll
    for (int ct = 0; ct < 8; ++ct) {
        const int col = ct * 16 + (lane & 15);
        const float bv = bz[col];
        #pragma unroll
        for (int j = 0; j < 4; ++j) {
            const int rr = rbase + j;
            if (rr < N) outp[(size_t)rr * stride + off + col] = f2bf(acc[ct][j] + bv);
        }
    }
}

// ==================== CSR build: two-level bucket counting sort ====================
__global__ __launch_bounds__(256) void zero_ints(int* __restrict__ p, int n)
{
    int i = blockIdx.x * 256 + threadIdx.x;
    if (i < n) p[i] = 0;
}

__global__ __launch_bounds__(256) void bkt_hist(const int* __restrict__ dst0,
                                                const int* __restrict__ dst1,
                                                int* __restrict__ bcnt, int nE)
{
    const int t = blockIdx.y;
    const int* dst = t ? dst1 : dst0;
    __shared__ int h[256];
    h[threadIdx.x] = 0;
    __syncthreads();
    for (int e = blockIdx.x * 256 + threadIdx.x; e < nE; e += gridDim.x * 256)
        atomicAdd(&h[dst[e] >> 8], 1);
    __syncthreads();
    if (h[threadIdx.x]) atomicAdd(&bcnt[t * 256 + threadIdx.x], h[threadIdx.x]);
}

__global__ __launch_bounds__(64) void bkt_scan(const int* __restrict__ bcnt,
                                               int* __restrict__ bbase,
                                               int* __restrict__ bcur,
                                               int* __restrict__ offs0,
                                               int* __restrict__ offs1, int N, int nE)
{
    if (threadIdx.x < 2) {
        int t = threadIdx.x;
        int run = 0;
        for (int i = 0; i < 256; ++i) {
            int v = bcnt[t * 256 + i];
            bbase[t * 256 + i] = run;
            bcur[t * 256 + i] = run;
            run += v;
        }
        if (t == 0) offs0[N] = nE; else offs1[N] = nE;
    }
}

__global__ __launch_bounds__(256) void bkt_part(const int* __restrict__ src0,
                                                const int* __restrict__ dst0,
                                                const int* __restrict__ src1,
                                                const int* __restrict__ dst1,
                                                int* __restrict__ bcur,
                                                unsigned* __restrict__ stage0,
                                                unsigned* __restrict__ stage1,
                                                int nE, int nbkt)
{
    const int t = blockIdx.y;
    const int* src = t ? src1 : src0;
    const int* dst = t ? dst1 : dst0;
    unsigned* stage = t ? stage1 : stage0;
    int* bc = bcur + t * 256;

    __shared__ unsigned ebuf[CHUNK];                   // 32 KB
    __shared__ int cnt[256], loff[256], cur[256], resv[256];

    const int tid  = threadIdx.x;
    const int e0   = blockIdx.x * CHUNK;
    const int ecnt = min(CHUNK, nE - e0);

    cnt[tid] = 0;
    __syncthreads();

    unsigned pk[CHUNK / 256];
    #pragma unroll
    for (int i = 0; i < CHUNK / 256; ++i) {
        const int le = i * 256 + tid;
        unsigned p = 0xFFFFFFFFu;
        if (le < ecnt) {
            int d = dst[e0 + le], s = src[e0 + le];
            p = ((unsigned)(d >> 8) << 24) | ((unsigned)(d & 255) << 16) | (unsigned)s;
            atomicAdd(&cnt[d >> 8], 1);
        }
        pk[i] = p;
    }
    __syncthreads();

    int v = cnt[tid];
    loff[tid] = v;
    __syncthreads();
    for (int off = 1; off < 256; off <<= 1) {
        int a = (tid >= off) ? loff[tid - off] : 0;
        __syncthreads();
        loff[tid] += a;
        __syncthreads();
    }
    int excl = loff[tid] - v;
    __syncthreads();
    loff[tid] = excl;
    cur[tid]  = excl;
    __syncthreads();

    #pragma unroll
    for (int i = 0; i < CHUNK / 256; ++i) {
        unsigned p = pk[i];
        if (p != 0xFFFFFFFFu) {
            int b = p >> 24;
            int pos = atomicAdd(&cur[b], 1);
            ebuf[pos] = p;
        }
    }
    __syncthreads();

    if (tid < nbkt && cnt[tid] > 0) resv[tid] = atomicAdd(&bc[tid], cnt[tid]);
    __syncthreads();

    const int wv = tid >> 6, ln = tid & 63;
    for (int b = wv; b < nbkt; b += 4) {
        const int c = cnt[b];
        if (c == 0) continue;
        const int lo = loff[b];
        const int rb = resv[b];
        for (int i = ln; i < c; i += 64) stage[rb + i] = ebuf[lo + i];
    }
}

__global__ __launch_bounds__(256) void bkt_fill(const unsigned* __restrict__ stage0,
                                                const unsigned* __restrict__ stage1,
                                                const int* __restrict__ bcnt,
                                                const int* __restrict__ bbase,
                                                int* __restrict__ offs0,
                                                int* __restrict__ offs1,
                                                int* __restrict__ col0,
                                                int* __restrict__ col1, int N)
{
    const int b = blockIdx.x, t = blockIdx.y;
    const unsigned* stage = t ? stage1 : stage0;
    int* offs = t ? offs1 : offs0;
    int* col  = t ? col1 : col0;
    const int base = bbase[t * 256 + b];
    int cb = bcnt[t * 256 + b];
    if (cb > CAP) cb = CAP;

    __shared__ unsigned ebuf[CAP];
    __shared__ int colbuf[CAP];
    __shared__ int dcnt[256], doff[256], dcur[256];

    const int tid = threadIdx.x;
    dcnt[tid] = 0;
    __syncthreads();

    for (int i = tid; i < cb; i += 256) {
        unsigned p = stage[base + i];
        ebuf[i] = p;
        atomicAdd(&dcnt[(p >> 16) & 255], 1);
    }
    __syncthreads();

    int v = dcnt[tid];
    doff[tid] = v;
    __syncthreads();
    for (int off = 1; off < 256; off <<= 1) {
        int a = (tid >= off) ? doff[tid - off] : 0;
        __syncthreads();
        doff[tid] += a;
        __syncthreads();
    }
    int excl = doff[tid] - v;
    dcur[tid] = excl;
    const int node = (b << 8) + tid;
    if (node < N) offs[node] = base + excl;
    __syncthreads();

    for (int i = tid; i < cb; i += 256) {
        unsigned p = ebuf[i];
        int pos = atomicAdd(&dcur[(p >> 16) & 255], 1);
        colbuf[pos] = (int)(p & 0xFFFFu);
    }
    __syncthreads();

    for (int i = tid; i < cb; i += 256) col[base + i] = colbuf[i];
}

// ==================== fused attention: 16 lanes/edge, 4 edges in flight ====================
template<bool BF16_OUT>
__global__ __launch_bounds__(256) void attn_gather(const ushort* __restrict__ QV,
                                                   const ushort* __restrict__ K,
                                                   const int* __restrict__ offs,
                                                   const int* __restrict__ col,
                                                   void* __restrict__ outv, int n)
{
    const int wid  = (blockIdx.x * 256 + threadIdx.x) >> 6;
    const int lane = threadIdx.x & 63;
    if (wid >= n) return;
    const int li = lane & 15;
    const int g  = lane >> 4;

    const int beg = offs[wid], end = offs[wid + 1];

    uint4 ku = ((const uint4*)(K + (size_t)wid * DD))[li];
    float kf[8];
    {
        float2 t;
        t = bfp(ku.x); kf[0]=t.x; kf[1]=t.y;
        t = bfp(ku.y); kf[2]=t.x; kf[3]=t.y;
        t = bfp(ku.z); kf[4]=t.x; kf[5]=t.y;
        t = bfp(ku.w); kf[6]=t.x; kf[7]=t.y;
    }

    float m = -__builtin_inff();
    float den = 0.f;
    float acc[8] = {0.f,0.f,0.f,0.f,0.f,0.f,0.f,0.f};

    int p = beg + g;
    uint4 qn = make_uint4(0,0,0,0), vn = make_uint4(0,0,0,0);
    if (p < end) {
        const ushort* row = QV + (size_t)col[p] * 256;
        qn = ((const uint4*)row)[li];
        vn = ((const uint4*)(row + 128))[li];
    }

    while (p < end) {
        uint4 qu = qn, vu = vn;
        const int pn = p + 4;
        if (pn < end) {
            const ushort* row = QV + (size_t)col[pn] * 256;
            qn = ((const uint4*)row)[li];
            vn = ((const uint4*)(row + 128))[li];
        }
        float2 t;
        float d;
        t = bfp(qu.x); d  = t.x*kf[0] + t.y*kf[1];
        t = bfp(qu.y); d += t.x*kf[2] + t.y*kf[3];
        t = bfp(qu.z); d += t.x*kf[4] + t.y*kf[5];
        t = bfp(qu.w); d += t.x*kf[6] + t.y*kf[7];
        d += __shfl_xor(d, 1);
        d += __shfl_xor(d, 2);
        d += __shfl_xor(d, 4);
        d += __shfl_xor(d, 8);
        float sc = d * 0.08838834764831845f;      // 1/sqrt(128)
        sc = sc > 0.f ? sc : 0.01f * sc;          // leaky_relu
        float nm = fmaxf(m, sc);
        float f  = __expf(m - nm);                // first iter: exp(-inf)=0
        float pe = __expf(sc - nm);
        den = den * f + pe;
        float2 v0 = bfp(vu.x), v1 = bfp(vu.y), v2 = bfp(vu.z), v3 = bfp(vu.w);
        acc[0] = acc[0]*f + pe*v0.x;  acc[1] = acc[1]*f + pe*v0.y;
        acc[2] = acc[2]*f + pe*v1.x;  acc[3] = acc[3]*f + pe*v1.y;
        acc[4] = acc[4]*f + pe*v2.x;  acc[5] = acc[5]*f + pe*v2.y;
        acc[6] = acc[6]*f + pe*v3.x;  acc[7] = acc[7]*f + pe*v3.y;
        m = nm;
        p = pn;
    }

    // merge the 4 groups
    float m1 = fmaxf(m, __shfl_xor(m, 16));
    float m2 = fmaxf(m1, __shfl_xor(m1, 32));
    float f = (den > 0.f) ? __expf(m - m2) : 0.f;   // guard -inf - -inf
    den *= f;
    den += __shfl_xor(den, 16);
    den += __shfl_xor(den, 32);
    #pragma unroll
    for (int j = 0; j < 8; ++j) {
        acc[j] *= f;
        acc[j] += __shfl_xor(acc[j], 16);
        acc[j] += __shfl_xor(acc[j], 32);
    }
    if (g == 0) {
        const float inv = den > 0.f ? 1.f / den : 0.f;
        if (BF16_OUT) {
            ushort* o = (ushort*)outv + (size_t)wid * DD + li * 8;
            bf16x8 h;
            #pragma unroll
            for (int j = 0; j < 8; ++j) h[j] = (short)f2bf(acc[j] * inv);
            *(bf16x8*)o = h;
        } else {
            float* o = (float*)outv + (size_t)wid * DD + li * 8;
            *(float4*)o       = make_float4(acc[0]*inv, acc[1]*inv, acc[2]*inv, acc[3]*inv);
            *(float4*)(o + 4) = make_float4(acc[4]*inv, acc[5]*inv, acc[6]*inv, acc[7]*inv);
        }
    }
}

// ==================== host ====================
extern "C" void kernel_launch(void* const* d_in, const int* in_sizes, int n_in,
                              void* d_out, int out_size, void* d_ws, size_t ws_size,
                              hipStream_t stream)
{
    const float* x_a    = (const float*)d_in[0];
    const float* x_b    = (const float*)d_in[1];
    const int*   ei_ab  = (const int*)d_in[2];
    const int*   ei_ba  = (const int*)d_in[3];
    const float* qkv_w  = (const float*)d_in[4];
    const float* qkv_b  = (const float*)d_in[5];
    const float* edge_W = (const float*)d_in[6];
    float* out = (float*)d_out;

    const int N = in_sizes[0] / DD;    // 50000
    const int E = in_sizes[2] / 2;     // 600000
    const int nbkt = (N + 255) >> 8;   // 196

    float* ws = (float*)d_ws;
    float* WC  = ws;                         // 4*128*128 f32
    float* BCq = WC + 4 * DD * DD;           // 4*128 f32
    float* B3  = BCq + 4 * DD;               // 4*384 f32
    ushort* W3P = (ushort*)(B3 + 4 * 384);   // 4*6144*8 bf16
    ushort* XA = W3P + (size_t)4 * 6144 * 8; // x_a bf16 [N*128]
    ushort* XB = XA + (size_t)N * DD;        // x_b bf16
    ushort* HA = XB + (size_t)N * DD;        // layer-1 out a bf16
    ushort* HB = HA + (size_t)N * DD;        // layer-1 out b bf16
    ushort* QV = HB + (size_t)N * DD;        // q|v interleaved [N*256] bf16
    ushort* FK = QV + (size_t)N * 256;       // k [N*128] bf16
    int* ip      = (int*)(FK + (size_t)N * DD);
    int* bcnt    = ip;                           // [512]
    int* bbase   = bcnt + 512;                   // [512]
    int* bcur    = bbase + 512;                  // [512]
    int* offs_ab = bcur + 512;                   // [N+1]
    int* offs_ba = offs_ab + (N + 1);            // [N+1]
    int* col_ab  = offs_ba + (N + 1);            // [E]
    int* col_ba  = col_ab + E;                   // [E]
    unsigned* stage0 = (unsigned*)(col_ba + E);  // [E]
    unsigned* stage1 = stage0 + E;               // [E]

    // ---- weight prep + input conversion ----
    {
        dim3 g1(64, 4);
        combine_all<<<g1, 256, 0, stream>>>(qkv_w, qkv_b, edge_W, WC, BCq);
        dim3 g2(24, 4);
        pack_all<<<g2, 256, 0, stream>>>(qkv_w, qkv_b, WC, BCq, W3P, B3);
        const int n8 = N * DD / 8;
        xcvt<<<2048, 256, 0, stream>>>(x_a, XA, n8);
        xcvt<<<2048, 256, 0, stream>>>(x_b, XB, n8);
    }

    // ---- CSR via two-level bucket sort (reused by both layers) ----
    const int* s_ab = ei_ab;  const int* d_ab = ei_ab + E;
    const int* s_ba = ei_ba;  const int* d_ba = ei_ba + E;
    {
        zero_ints<<<2, 256, 0, stream>>>(bcnt, 512);
        dim3 hg(128, 2);
        bkt_hist<<<hg, 256, 0, stream>>>(d_ab, d_ba, bcnt, E);
        bkt_scan<<<1, 64, 0, stream>>>(bcnt, bbase, bcur, offs_ab, offs_ba, N, E);
        dim3 pg((E + CHUNK - 1) / CHUNK, 2);
        bkt_part<<<pg, 256, 0, stream>>>(s_ab, d_ab, s_ba, d_ba, bcur,
                                         stage0, stage1, E, nbkt);
        dim3 fg(nbkt, 2);
        bkt_fill<<<fg, 256, 0, stream>>>(stage0, stage1, bcnt, bbase,
                                         offs_ab, offs_ba, col_ab, col_ba, N);
    }

    const dim3 gemm_grid((N + 63) / 64, 3);
    const int ag_grid = (N + 3) / 4;

    auto attend = [&](int z, const ushort* Xsrc, const ushort* Xdst, bool relu_in,
                      const int* offs, const int* col, void* outbuf, bool bf16_out) {
        const ushort* Bp = W3P + (size_t)z * 6144 * 8;
        const float* bz  = B3 + (size_t)z * 384;
        if (relu_in)
            gemm_mfma<true ><<<gemm_grid, 256, 0, stream>>>(Xsrc, Xdst, Bp, bz, QV, FK, N);
        else
            gemm_mfma<false><<<gemm_grid, 256, 0, stream>>>(Xsrc, Xdst, Bp, bz, QV, FK, N);
        if (bf16_out)
            attn_gather<true ><<<ag_grid, 256, 0, stream>>>(QV, FK, offs, col, outbuf, N);
        else
            attn_gather<false><<<ag_grid, 256, 0, stream>>>(QV, FK, offs, col, outbuf, N);
    };

    // layer 1 (bf16 H outputs)
    attend(0, XA, XB, false, offs_ab, col_ab, HB, true);   // a->b, dst b
    attend(1, XB, XA, false, offs_ba, col_ba, HA, true);   // b->a, dst a
    // layer 2 (relu fused into GEMM A-loads; f32 final outputs)
    float* o_a = out;
    float* o_b = out + (size_t)N * DD;
    attend(2, HA, HB, true, offs_ab, col_ab, o_b, false);
    attend(3, HB, HA, true, offs_ba, col_ba, o_a, false);
}

// Round 10
// 352.778 us; speedup vs baseline: 2.7638x; 1.0802x over previous
//
#include <hip/hip_runtime.h>
#include <math.h>

#define DD 128
#define CHUNK 8192
#define CAP 5120

typedef __attribute__((ext_vector_type(8))) short bf16x8;  // 8 bf16 (4 VGPR)
typedef __attribute__((ext_vector_type(4))) float f32x4;   // 4 fp32 acc

__device__ __forceinline__ ushort f2bf(float f) {
    union { float f; unsigned u; } v; v.f = f;
    unsigned r = v.u + 0x7fff + ((v.u >> 16) & 1);   // RNE
    return (ushort)(r >> 16);
}

__device__ __forceinline__ float2 bfp(unsigned u) {
    union { unsigned x; float f; } a, b;
    a.x = u << 16;
    b.x = u & 0xffff0000u;
    return make_float2(a.f, b.f);
}

// ==================== weight prep (once per launch) ====================
__global__ __launch_bounds__(256) void combine_all(const float* __restrict__ qkv_w,
                                                   const float* __restrict__ qkv_b,
                                                   const float* __restrict__ edge_W,
                                                   float* __restrict__ WC,
                                                   float* __restrict__ BCq)
{
    const int z = blockIdx.y;          // (L<<1)|t
    const int L = z >> 1, t = z & 1;
    const float* wq = qkv_w + (((size_t)L * 2 + t) * 3 + 0) * DD * DD;
    const float* bq = qkv_b + (((size_t)L * 2 + t) * 3 + 0) * DD;
    const float* We = edge_W + ((size_t)L * 2 + t) * DD * DD;
    float* Wz = WC + (size_t)z * DD * DD;
    float* Bz = BCq + (size_t)z * DD;

    const int tid = threadIdx.x;
    const int i = blockIdx.x * 2 + (tid >> 7);
    const int j = tid & 127;
    float sum = 0.f;
    for (int k = 0; k < DD; ++k) sum = fmaf(wq[i * DD + k], We[k * DD + j], sum);
    Wz[i * DD + j] = sum;
    if (blockIdx.x == 0 && tid < DD) {
        float s2 = 0.f;
        for (int k = 0; k < DD; ++k) s2 = fmaf(bq[k], We[k * DD + j], s2);
        Bz[j] = s2;
    }
}

// Pack per z=(L,t): planes [q(Wc z) | v(wv L,t) | k(wk L,t)]  (k now SAME type t)
__global__ __launch_bounds__(256) void pack_all(const float* __restrict__ qkv_w,
                                                const float* __restrict__ qkv_b,
                                                const float* __restrict__ WC,
                                                const float* __restrict__ BCq,
                                                ushort* __restrict__ W3P,
                                                float* __restrict__ B3)
{
    const int z = blockIdx.y;
    const int L = z >> 1, t = z & 1;
    const int ci = blockIdx.x * 256 + threadIdx.x;     // 0..6143
    const int cb = ci >> 11;
    const int ct = (ci >> 8) & 7;
    const int ks = (ci >> 6) & 3;
    const int l  = ci & 63;
    const int c3 = cb * 128 + ct * 16 + (l & 15);
    const int k0 = ks * 32 + (l >> 4) * 8;

    const float* wv = qkv_w + (((size_t)L * 2 + t) * 3 + 2) * DD * DD;
    const float* wk = qkv_w + (((size_t)L * 2 + t) * 3 + 1) * DD * DD;
    const float* src;
    int cc;
    if (c3 < 128)      { src = WC + (size_t)z * DD * DD; cc = c3; }
    else if (c3 < 256) { src = wv; cc = c3 - 128; }
    else               { src = wk; cc = c3 - 256; }

    ushort h[8];
    #pragma unroll
    for (int j = 0; j < 8; ++j) h[j] = f2bf(src[(size_t)(k0 + j) * DD + cc]);
    ushort* dst = W3P + (size_t)z * 6144 * 8 + (size_t)ci * 8;
    #pragma unroll
    for (int j = 0; j < 8; ++j) dst[j] = h[j];

    if (ci < 384) {
        float bv;
        if (ci < 128)      bv = BCq[(size_t)z * DD + ci];
        else if (ci < 256) bv = qkv_b[(((size_t)L * 2 + t) * 3 + 2) * DD + (ci - 128)];
        else               bv = qkv_b[(((size_t)L * 2 + t) * 3 + 1) * DD + (ci - 256)];
        B3[(size_t)z * 384 + ci] = bv;
    }
}

// ==================== fused per-layer MFMA GEMM (LDS-free) ====================
// grid (ceil(N/64), 2): block (x, t) computes q,v,k for 64 rows of node type t.
// A-frags loaded once from X_t (f32 layer-1 / bf16+relu layer-2); 96 MFMAs.
template<bool F32_IN, bool RELU_IN>
__global__ __launch_bounds__(256, 4) void gemm_mfma(const void* __restrict__ Xav,
                                                    const void* __restrict__ Xbv,
                                                    const ushort* __restrict__ WpL,  // layer base, 2 z-blocks
                                                    const float* __restrict__ bL,    // layer base, 2*384
                                                    ushort* __restrict__ QVa,
                                                    ushort* __restrict__ FKa,
                                                    ushort* __restrict__ QVb,
                                                    ushort* __restrict__ FKb,
                                                    int N)
{
    const int t = blockIdx.y;
    ushort* QV = t ? QVb : QVa;
    ushort* FK = t ? FKb : FKa;
    const ushort* Wz = WpL + (size_t)t * 49152;   // 6144*8 per z
    const float* bz0 = bL + (size_t)t * 384;

    const int wave = threadIdx.x >> 6;
    const int lane = threadIdx.x & 63;
    const int row0 = blockIdx.x * 64 + wave * 16;
    const int arow = row0 + (lane & 15);
    const bool aok = arow < N;
    const int kcol = (lane >> 4) * 8;

    bf16x8 a[4];
    if (F32_IN) {
        const float* X = (const float*)(t ? Xbv : Xav);
        const float* xr = X + (size_t)arow * DD + kcol;
        #pragma unroll
        for (int ks = 0; ks < 4; ++ks) {
            bf16x8 h = (bf16x8){0,0,0,0,0,0,0,0};
            if (aok) {
                float4 v0 = *(const float4*)&xr[ks * 32];
                float4 v1 = *(const float4*)&xr[ks * 32 + 4];
                h[0]=(short)f2bf(v0.x); h[1]=(short)f2bf(v0.y); h[2]=(short)f2bf(v0.z); h[3]=(short)f2bf(v0.w);
                h[4]=(short)f2bf(v1.x); h[5]=(short)f2bf(v1.y); h[6]=(short)f2bf(v1.z); h[7]=(short)f2bf(v1.w);
            }
            a[ks] = h;
        }
    } else {
        const ushort* X = (const ushort*)(t ? Xbv : Xav);
        const ushort* xr = X + (size_t)arow * DD + kcol;
        #pragma unroll
        for (int ks = 0; ks < 4; ++ks) {
            bf16x8 h = (bf16x8){0,0,0,0,0,0,0,0};
            if (aok) h = *(const bf16x8*)&xr[ks * 32];
            if (RELU_IN) {
                #pragma unroll
                for (int j = 0; j < 8; ++j)
                    h[j] = (short)(((ushort)h[j] & 0x8000u) ? 0 : (ushort)h[j]);
            }
            a[ks] = h;
        }
    }

    const int rbase = row0 + (lane >> 4) * 4;
    #pragma unroll
    for (int p = 0; p < 3; ++p) {
        const ushort* Bp = Wz + (size_t)p * 16384;
        const float* bz = bz0 + p * 128;
        ushort* outp   = (p == 2) ? FK : QV;
        const int stride = (p == 2) ? 128 : 256;
        const int off    = (p == 1) ? 128 : 0;

        f32x4 acc[8];
        #pragma unroll
        for (int ct = 0; ct < 8; ++ct) {
            acc[ct] = (f32x4){0.f, 0.f, 0.f, 0.f};
            #pragma unroll
            for (int ks = 0; ks < 4; ++ks) {
                bf16x8 b = *(const bf16x8*)&Bp[(size_t)((ct * 4 + ks) * 64 + lane) * 8];
                acc[ct] = __builtin_amdgcn_mfma_f32_16x16x32_bf16(a[ks], b, acc[ct], 0, 0, 0);
            }
        }
        #pragma unroll
        for (int ct = 0; ct < 8; ++ct) {
            const int col = ct * 16 + (lane & 15);
            const float bv = bz[col];
            #pragma unroll
            for (int j = 0; j < 4; ++j) {
                const int rr = rbase + j;
                if (rr < N) outp[(size_t)rr * stride + off + col] = f2bf(acc[ct][j] + bv);
            }
        }
    }
}

// ==================== CSR build: two-level bucket counting sort ====================
__global__ __launch_bounds__(256) void zero_ints(int* __restrict__ p, int n)
{
    int i = blockIdx.x * 256 + threadIdx.x;
    if (i < n) p[i] = 0;
}

__global__ __launch_bounds__(256) void bkt_hist(const int* __restrict__ dst0,
                                                const int* __restrict__ dst1,
                                                int* __restrict__ bcnt, int nE)
{
    const int t = blockIdx.y;
    const int* dst = t ? dst1 : dst0;
    __shared__ int h[256];
    h[threadIdx.x] = 0;
    __syncthreads();
    for (int e = blockIdx.x * 256 + threadIdx.x; e < nE; e += gridDim.x * 256)
        atomicAdd(&h[dst[e] >> 8], 1);
    __syncthreads();
    if (h[threadIdx.x]) atomicAdd(&bcnt[t * 256 + threadIdx.x], h[threadIdx.x]);
}

__global__ __launch_bounds__(64) void bkt_scan(const int* __restrict__ bcnt,
                                               int* __restrict__ bbase,
                                               int* __restrict__ bcur,
                                               int* __restrict__ offs0,
                                               int* __restrict__ offs1, int N, int nE)
{
    if (threadIdx.x < 2) {
        int t = threadIdx.x;
        int run = 0;
        for (int i = 0; i < 256; ++i) {
            int v = bcnt[t * 256 + i];
            bbase[t * 256 + i] = run;
            bcur[t * 256 + i] = run;
            run += v;
        }
        if (t == 0) offs0[N] = nE; else offs1[N] = nE;
    }
}

__global__ __launch_bounds__(256) void bkt_part(const int* __restrict__ src0,
                                                const int* __restrict__ dst0,
                                                const int* __restrict__ src1,
                                                const int* __restrict__ dst1,
                                                int* __restrict__ bcur,
                                                unsigned* __restrict__ stage0,
                                                unsigned* __restrict__ stage1,
                                                int nE, int nbkt)
{
    const int t = blockIdx.y;
    const int* src = t ? src1 : src0;
    const int* dst = t ? dst1 : dst0;
    unsigned* stage = t ? stage1 : stage0;
    int* bc = bcur + t * 256;

    __shared__ unsigned ebuf[CHUNK];                   // 32 KB
    __shared__ int cnt[256], loff[256], cur[256], resv[256];

    const int tid  = threadIdx.x;
    const int e0   = blockIdx.x * CHUNK;
    const int ecnt = min(CHUNK, nE - e0);

    cnt[tid] = 0;
    __syncthreads();

    unsigned pk[CHUNK / 256];
    #pragma unroll
    for (int i = 0; i < CHUNK / 256; ++i) {
        const int le = i * 256 + tid;
        unsigned p = 0xFFFFFFFFu;
        if (le < ecnt) {
            int d = dst[e0 + le], s = src[e0 + le];
            p = ((unsigned)(d >> 8) << 24) | ((unsigned)(d & 255) << 16) | (unsigned)s;
            atomicAdd(&cnt[d >> 8], 1);
        }
        pk[i] = p;
    }
    __syncthreads();

    int v = cnt[tid];
    loff[tid] = v;
    __syncthreads();
    for (int off = 1; off < 256; off <<= 1) {
        int a = (tid >= off) ? loff[tid - off] : 0;
        __syncthreads();
        loff[tid] += a;
        __syncthreads();
    }
    int excl = loff[tid] - v;
    __syncthreads();
    loff[tid] = excl;
    cur[tid]  = excl;
    __syncthreads();

    #pragma unroll
    for (int i = 0; i < CHUNK / 256; ++i) {
        unsigned p = pk[i];
        if (p != 0xFFFFFFFFu) {
            int b = p >> 24;
            int pos = atomicAdd(&cur[b], 1);
            ebuf[pos] = p;
        }
    }
    __syncthreads();

    if (tid < nbkt && cnt[tid] > 0) resv[tid] = atomicAdd(&bc[tid], cnt[tid]);
    __syncthreads();

    const int wv = tid >> 6, ln = tid & 63;
    for (int b = wv; b < nbkt; b += 4) {
        const int c = cnt[b];
        if (c == 0) continue;
        const int lo = loff[b];
        const int rb = resv[b];
        for (int i = ln; i < c; i += 64) stage[rb + i] = ebuf[lo + i];
    }
}

__global__ __launch_bounds__(256) void bkt_fill(const unsigned* __restrict__ stage0,
                                                const unsigned* __restrict__ stage1,
                                                const int* __restrict__ bcnt,
                                                const int* __restrict__ bbase,
                                                int* __restrict__ offs0,
                                                int* __restrict__ offs1,
                                                int* __restrict__ col0,
                                                int* __restrict__ col1, int N)
{
    const int b = blockIdx.x, t = blockIdx.y;
    const unsigned* stage = t ? stage1 : stage0;
    int* offs = t ? offs1 : offs0;
    int* col  = t ? col1 : col0;
    const int base = bbase[t * 256 + b];
    int cb = bcnt[t * 256 + b];
    if (cb > CAP) cb = CAP;

    __shared__ unsigned ebuf[CAP];
    __shared__ int colbuf[CAP];
    __shared__ int dcnt[256], doff[256], dcur[256];

    const int tid = threadIdx.x;
    dcnt[tid] = 0;
    __syncthreads();

    for (int i = tid; i < cb; i += 256) {
        unsigned p = stage[base + i];
        ebuf[i] = p;
        atomicAdd(&dcnt[(p >> 16) & 255], 1);
    }
    __syncthreads();

    int v = dcnt[tid];
    doff[tid] = v;
    __syncthreads();
    for (int off = 1; off < 256; off <<= 1) {
        int a = (tid >= off) ? doff[tid - off] : 0;
        __syncthreads();
        doff[tid] += a;
        __syncthreads();
    }
    int excl = doff[tid] - v;
    dcur[tid] = excl;
    const int node = (b << 8) + tid;
    if (node < N) offs[node] = base + excl;
    __syncthreads();

    for (int i = tid; i < cb; i += 256) {
        unsigned p = ebuf[i];
        int pos = atomicAdd(&dcur[(p >> 16) & 255], 1);
        colbuf[pos] = (int)(p & 0xFFFFu);
    }
    __syncthreads();

    for (int i = tid; i < cb; i += 256) col[base + i] = colbuf[i];
}

// ==================== fused attention: 16 lanes/edge, 4 edges in flight ====================
template<bool BF16_OUT>
__global__ __launch_bounds__(256) void attn_gather(const ushort* __restrict__ QV,
                                                   const ushort* __restrict__ K,
                                                   const int* __restrict__ offs,
                                                   const int* __restrict__ col,
                                                   void* __restrict__ outv, int n)
{
    const int wid  = (blockIdx.x * 256 + threadIdx.x) >> 6;
    const int lane = threadIdx.x & 63;
    if (wid >= n) return;
    const int li = lane & 15;
    const int g  = lane >> 4;

    const int beg = offs[wid], end = offs[wid + 1];

    uint4 ku = ((const uint4*)(K + (size_t)wid * DD))[li];
    float kf[8];
    {
        float2 t;
        t = bfp(ku.x); kf[0]=t.x; kf[1]=t.y;
        t = bfp(ku.y); kf[2]=t.x; kf[3]=t.y;
        t = bfp(ku.z); kf[4]=t.x; kf[5]=t.y;
        t = bfp(ku.w); kf[6]=t.x; kf[7]=t.y;
    }

    float m = -__builtin_inff();
    float den = 0.f;
    float acc[8] = {0.f,0.f,0.f,0.f,0.f,0.f,0.f,0.f};

    int p = beg + g;
    uint4 qn = make_uint4(0,0,0,0), vn = make_uint4(0,0,0,0);
    if (p < end) {
        const ushort* row = QV + (size_t)col[p] * 256;
        qn = ((const uint4*)row)[li];
        vn = ((const uint4*)(row + 128))[li];
    }

    while (p < end) {
        uint4 qu = qn, vu = vn;
        const int pn = p + 4;
        if (pn < end) {
            const ushort* row = QV + (size_t)col[pn] * 256;
            qn = ((const uint4*)row)[li];
            vn = ((const uint4*)(row + 128))[li];
        }
        float2 t;
        float d;
        t = bfp(qu.x); d  = t.x*kf[0] + t.y*kf[1];
        t = bfp(qu.y); d += t.x*kf[2] + t.y*kf[3];
        t = bfp(qu.z); d += t.x*kf[4] + t.y*kf[5];
        t = bfp(qu.w); d += t.x*kf[6] + t.y*kf[7];
        d += __shfl_xor(d, 1);
        d += __shfl_xor(d, 2);
        d += __shfl_xor(d, 4);
        d += __shfl_xor(d, 8);
        float sc = d * 0.08838834764831845f;      // 1/sqrt(128)
        sc = sc > 0.f ? sc : 0.01f * sc;          // leaky_relu
        float nm = fmaxf(m, sc);
        float f  = __expf(m - nm);                // first iter: exp(-inf)=0
        float pe = __expf(sc - nm);
        den = den * f + pe;
        float2 v0 = bfp(vu.x), v1 = bfp(vu.y), v2 = bfp(vu.z), v3 = bfp(vu.w);
        acc[0] = acc[0]*f + pe*v0.x;  acc[1] = acc[1]*f + pe*v0.y;
        acc[2] = acc[2]*f + pe*v1.x;  acc[3] = acc[3]*f + pe*v1.y;
        acc[4] = acc[4]*f + pe*v2.x;  acc[5] = acc[5]*f + pe*v2.y;
        acc[6] = acc[6]*f + pe*v3.x;  acc[7] = acc[7]*f + pe*v3.y;
        m = nm;
        p = pn;
    }

    // merge the 4 groups
    float m1 = fmaxf(m, __shfl_xor(m, 16));
    float m2 = fmaxf(m1, __shfl_xor(m1, 32));
    float f = (den > 0.f) ? __expf(m - m2) : 0.f;   // guard -inf - -inf
    den *= f;
    den += __shfl_xor(den, 16);
    den += __shfl_xor(den, 32);
    #pragma unroll
    for (int j = 0; j < 8; ++j) {
        acc[j] *= f;
        acc[j] += __shfl_xor(acc[j], 16);
        acc[j] += __shfl_xor(acc[j], 32);
    }
    if (g == 0) {
        const float inv = den > 0.f ? 1.f / den : 0.f;
        if (BF16_OUT) {
            ushort* o = (ushort*)outv + (size_t)wid * DD + li * 8;
            bf16x8 h;
            #pragma unroll
            for (int j = 0; j < 8; ++j) h[j] = (short)f2bf(acc[j] * inv);
            *(bf16x8*)o = h;
        } else {
            float* o = (float*)outv + (size_t)wid * DD + li * 8;
            *(float4*)o       = make_float4(acc[0]*inv, acc[1]*inv, acc[2]*inv, acc[3]*inv);
            *(float4*)(o + 4) = make_float4(acc[4]*inv, acc[5]*inv, acc[6]*inv, acc[7]*inv);
        }
    }
}

// ==================== host ====================
extern "C" void kernel_launch(void* const* d_in, const int* in_sizes, int n_in,
                              void* d_out, int out_size, void* d_ws, size_t ws_size,
                              hipStream_t stream)
{
    const float* x_a    = (const float*)d_in[0];
    const float* x_b    = (const float*)d_in[1];
    const int*   ei_ab  = (const int*)d_in[2];
    const int*   ei_ba  = (const int*)d_in[3];
    const float* qkv_w  = (const float*)d_in[4];
    const float* qkv_b  = (const float*)d_in[5];
    const float* edge_W = (const float*)d_in[6];
    float* out = (float*)d_out;

    const int N = in_sizes[0] / DD;    // 50000
    const int E = in_sizes[2] / 2;     // 600000
    const int nbkt = (N + 255) >> 8;   // 196

    float* ws = (float*)d_ws;
    float* WC  = ws;                         // 4*128*128 f32
    float* BCq = WC + 4 * DD * DD;           // 4*128 f32
    float* B3  = BCq + 4 * DD;               // 4*384 f32
    ushort* W3P = (ushort*)(B3 + 4 * 384);   // 4*49152 bf16
    ushort* HA  = W3P + (size_t)4 * 49152;   // layer-1 out a bf16 [N*128]
    ushort* HB  = HA + (size_t)N * DD;       // layer-1 out b bf16
    ushort* QVa = HB + (size_t)N * DD;       // q|v type a [N*256] bf16
    ushort* QVb = QVa + (size_t)N * 256;     // q|v type b
    ushort* FKa = QVb + (size_t)N * 256;     // k type a [N*128] bf16
    ushort* FKb = FKa + (size_t)N * DD;      // k type b
    int* ip      = (int*)(FKb + (size_t)N * DD);
    int* bcnt    = ip;                           // [512]
    int* bbase   = bcnt + 512;                   // [512]
    int* bcur    = bbase + 512;                  // [512]
    int* offs_ab = bcur + 512;                   // [N+1]
    int* offs_ba = offs_ab + (N + 1);            // [N+1]
    int* col_ab  = offs_ba + (N + 1);            // [E]
    int* col_ba  = col_ab + E;                   // [E]
    unsigned* stage0 = (unsigned*)(col_ba + E);  // [E]
    unsigned* stage1 = stage0 + E;               // [E]

    // ---- weight prep ----
    {
        dim3 g1(64, 4);
        combine_all<<<g1, 256, 0, stream>>>(qkv_w, qkv_b, edge_W, WC, BCq);
        dim3 g2(24, 4);
        pack_all<<<g2, 256, 0, stream>>>(qkv_w, qkv_b, WC, BCq, W3P, B3);
    }

    // ---- CSR via two-level bucket sort (reused by both layers) ----
    const int* s_ab = ei_ab;  const int* d_ab = ei_ab + E;
    const int* s_ba = ei_ba;  const int* d_ba = ei_ba + E;
    {
        zero_ints<<<2, 256, 0, stream>>>(bcnt, 512);
        dim3 hg(128, 2);
        bkt_hist<<<hg, 256, 0, stream>>>(d_ab, d_ba, bcnt, E);
        bkt_scan<<<1, 64, 0, stream>>>(bcnt, bbase, bcur, offs_ab, offs_ba, N, E);
        dim3 pg((E + CHUNK - 1) / CHUNK, 2);
        bkt_part<<<pg, 256, 0, stream>>>(s_ab, d_ab, s_ba, d_ba, bcur,
                                         stage0, stage1, E, nbkt);
        dim3 fg(nbkt, 2);
        bkt_fill<<<fg, 256, 0, stream>>>(stage0, stage1, bcnt, bbase,
                                         offs_ab, offs_ba, col_ab, col_ba, N);
    }

    const dim3 gemm_grid((N + 63) / 64, 2);
    const int ag_grid = (N + 3) / 4;

    // ---- layer 1: one fused GEMM (f32 inputs), two attends (bf16 H out) ----
    gemm_mfma<true, false><<<gemm_grid, 256, 0, stream>>>(
        x_a, x_b, W3P, B3, QVa, FKa, QVb, FKb, N);
    attn_gather<true><<<ag_grid, 256, 0, stream>>>(QVa, FKb, offs_ab, col_ab, HB, N);
    attn_gather<true><<<ag_grid, 256, 0, stream>>>(QVb, FKa, offs_ba, col_ba, HA, N);

    // ---- layer 2: fused GEMM (bf16+relu inputs), two attends (f32 out) ----
    float* o_a = out;
    float* o_b = out + (size_t)N * DD;
    gemm_mfma<false, true><<<gemm_grid, 256, 0, stream>>>(
        HA, HB, W3P + (size_t)2 * 49152, B3 + 2 * 384, QVa, FKa, QVb, FKb, N);
    attn_gather<false><<<ag_grid, 256, 0, stream>>>(QVa, FKb, offs_ab, col_ab, o_b, N);
    attn_gather<false><<<ag_grid, 256, 0, stream>>>(QVb, FKa, offs_ba, col_ba, o_a, N);
}

// Round 11
// 344.750 us; speedup vs baseline: 2.8281x; 1.0233x over previous
//
#include <hip/hip_runtime.h>
#include <math.h>

#define DD 128
#define CHUNK 8192
#define CAP 5120

typedef __attribute__((ext_vector_type(8))) short bf16x8;  // 8 bf16 (4 VGPR)
typedef __attribute__((ext_vector_type(4))) float f32x4;   // 4 fp32 acc

__device__ __forceinline__ ushort f2bf(float f) {
    union { float f; unsigned u; } v; v.f = f;
    unsigned r = v.u + 0x7fff + ((v.u >> 16) & 1);   // RNE
    return (ushort)(r >> 16);
}

__device__ __forceinline__ float2 bfp(unsigned u) {
    union { unsigned x; float f; } a, b;
    a.x = u << 16;
    b.x = u & 0xffff0000u;
    return make_float2(a.f, b.f);
}

// ==================== weight prep (once per launch) ====================
__global__ __launch_bounds__(256) void combine_all(const float* __restrict__ qkv_w,
                                                   const float* __restrict__ qkv_b,
                                                   const float* __restrict__ edge_W,
                                                   float* __restrict__ WC,
                                                   float* __restrict__ BCq)
{
    const int z = blockIdx.y;          // (L<<1)|t
    const int L = z >> 1, t = z & 1;
    const float* wq = qkv_w + (((size_t)L * 2 + t) * 3 + 0) * DD * DD;
    const float* bq = qkv_b + (((size_t)L * 2 + t) * 3 + 0) * DD;
    const float* We = edge_W + ((size_t)L * 2 + t) * DD * DD;
    float* Wz = WC + (size_t)z * DD * DD;
    float* Bz = BCq + (size_t)z * DD;

    const int tid = threadIdx.x;
    const int i = blockIdx.x * 2 + (tid >> 7);
    const int j = tid & 127;
    float sum = 0.f;
    for (int k = 0; k < DD; ++k) sum = fmaf(wq[i * DD + k], We[k * DD + j], sum);
    Wz[i * DD + j] = sum;
    if (blockIdx.x == 0 && tid < DD) {
        float s2 = 0.f;
        for (int k = 0; k < DD; ++k) s2 = fmaf(bq[k], We[k * DD + j], s2);
        Bz[j] = s2;
    }
}

// Pack per z=(L,t): planes [q(Wc z) | v(wv L,t) | k(wk L,t)]  (k SAME type t)
__global__ __launch_bounds__(256) void pack_all(const float* __restrict__ qkv_w,
                                                const float* __restrict__ qkv_b,
                                                const float* __restrict__ WC,
                                                const float* __restrict__ BCq,
                                                ushort* __restrict__ W3P,
                                                float* __restrict__ B3)
{
    const int z = blockIdx.y;
    const int L = z >> 1, t = z & 1;
    const int ci = blockIdx.x * 256 + threadIdx.x;     // 0..6143
    const int cb = ci >> 11;
    const int ct = (ci >> 8) & 7;
    const int ks = (ci >> 6) & 3;
    const int l  = ci & 63;
    const int c3 = cb * 128 + ct * 16 + (l & 15);
    const int k0 = ks * 32 + (l >> 4) * 8;

    const float* wv = qkv_w + (((size_t)L * 2 + t) * 3 + 2) * DD * DD;
    const float* wk = qkv_w + (((size_t)L * 2 + t) * 3 + 1) * DD * DD;
    const float* src;
    int cc;
    if (c3 < 128)      { src = WC + (size_t)z * DD * DD; cc = c3; }
    else if (c3 < 256) { src = wv; cc = c3 - 128; }
    else               { src = wk; cc = c3 - 256; }

    ushort h[8];
    #pragma unroll
    for (int j = 0; j < 8; ++j) h[j] = f2bf(src[(size_t)(k0 + j) * DD + cc]);
    ushort* dst = W3P + (size_t)z * 6144 * 8 + (size_t)ci * 8;
    #pragma unroll
    for (int j = 0; j < 8; ++j) dst[j] = h[j];

    if (ci < 384) {
        float bv;
        if (ci < 128)      bv = BCq[(size_t)z * DD + ci];
        else if (ci < 256) bv = qkv_b[(((size_t)L * 2 + t) * 3 + 2) * DD + (ci - 128)];
        else               bv = qkv_b[(((size_t)L * 2 + t) * 3 + 1) * DD + (ci - 256)];
        B3[(size_t)z * 384 + ci] = bv;
    }
}

// ==================== MFMA GEMM: B-plane in LDS, A register-direct ====================
// grid (ceil(N/64), 6): y = t*3 + p.  p: 0->q (QV[:,0:128]), 1->v (QV[:,128:256]), 2->k (FK).
template<bool F32_IN, bool RELU_IN>
__global__ __launch_bounds__(256, 4) void gemm_mfma(const void* __restrict__ Xav,
                                                    const void* __restrict__ Xbv,
                                                    const ushort* __restrict__ WpL,  // layer base
                                                    const float* __restrict__ bL,    // layer base
                                                    ushort* __restrict__ QVa,
                                                    ushort* __restrict__ FKa,
                                                    ushort* __restrict__ QVb,
                                                    ushort* __restrict__ FKb,
                                                    int N)
{
    const int t = (blockIdx.y >= 3) ? 1 : 0;
    const int p = blockIdx.y - t * 3;
    ushort* QV = t ? QVb : QVa;
    ushort* FK = t ? FKb : FKa;
    const ushort* Bp = WpL + (size_t)t * 49152 + (size_t)p * 16384;
    const float* bz = bL + t * 384 + p * 128;
    ushort* outp   = (p == 2) ? FK : QV;
    const int stride = (p == 2) ? 128 : 256;
    const int off    = (p == 1) ? 128 : 0;

    __shared__ ushort Bs[16384];   // 32 KB, frag-linear

    const int tid  = threadIdx.x;
    const int wave = tid >> 6;
    const int lane = tid & 63;
    const int row0 = blockIdx.x * 64 + wave * 16;
    const int arow = row0 + (lane & 15);
    const bool aok = arow < N;
    const int kcol = (lane >> 4) * 8;

    // stage B: linear 16B copy (2048 chunks, 8 per thread) — conflict-free
    #pragma unroll
    for (int i = 0; i < 8; ++i) {
        const int c = tid + i * 256;
        *(float4*)&Bs[(size_t)c * 8] = ((const float4*)Bp)[c];
    }

    // A fragments straight from global (16 rows x 64B lines per instruction)
    bf16x8 a[4];
    if (F32_IN) {
        const float* X = (const float*)(t ? Xbv : Xav);
        const float* xr = X + (size_t)arow * DD + kcol;
        #pragma unroll
        for (int ks = 0; ks < 4; ++ks) {
            bf16x8 h = (bf16x8){0,0,0,0,0,0,0,0};
            if (aok) {
                float4 v0 = *(const float4*)&xr[ks * 32];
                float4 v1 = *(const float4*)&xr[ks * 32 + 4];
                h[0]=(short)f2bf(v0.x); h[1]=(short)f2bf(v0.y); h[2]=(short)f2bf(v0.z); h[3]=(short)f2bf(v0.w);
                h[4]=(short)f2bf(v1.x); h[5]=(short)f2bf(v1.y); h[6]=(short)f2bf(v1.z); h[7]=(short)f2bf(v1.w);
            }
            a[ks] = h;
        }
    } else {
        const ushort* X = (const ushort*)(t ? Xbv : Xav);
        const ushort* xr = X + (size_t)arow * DD + kcol;
        #pragma unroll
        for (int ks = 0; ks < 4; ++ks) {
            bf16x8 h = (bf16x8){0,0,0,0,0,0,0,0};
            if (aok) h = *(const bf16x8*)&xr[ks * 32];
            if (RELU_IN) {
                #pragma unroll
                for (int j = 0; j < 8; ++j)
                    h[j] = (short)(((ushort)h[j] & 0x8000u) ? 0 : (ushort)h[j]);
            }
            a[ks] = h;
        }
    }
    __syncthreads();

    f32x4 acc[8];
    #pragma unroll
    for (int ct = 0; ct < 8; ++ct) {
        acc[ct] = (f32x4){0.f, 0.f, 0.f, 0.f};
        #pragma unroll
        for (int ks = 0; ks < 4; ++ks) {
            bf16x8 b = *(const bf16x8*)&Bs[(size_t)((ct * 4 + ks) * 64 + lane) * 8];
            acc[ct] = __builtin_amdgcn_mfma_f32_16x16x32_bf16(a[ks], b, acc[ct], 0, 0, 0);
        }
    }

    // store bf16: C/D map col=lane&15, row=(lane>>4)*4+reg
    const int rbase = row0 + (lane >> 4) * 4;
    #pragma unroll
    for (int ct = 0; ct < 8; ++ct) {
        const int col = ct * 16 + (lane & 15);
        const float bv = bz[col];
        #pragma unroll
        for (int j = 0; j < 4; ++j) {
            const int rr = rbase + j;
            if (rr < N) outp[(size_t)rr * stride + off + col] = f2bf(acc[ct][j] + bv);
        }
    }
}

// ==================== CSR build: two-level bucket counting sort ====================
__global__ __launch_bounds__(256) void zero_ints(int* __restrict__ p, int n)
{
    int i = blockIdx.x * 256 + threadIdx.x;
    if (i < n) p[i] = 0;
}

__global__ __launch_bounds__(256) void bkt_hist(const int* __restrict__ dst0,
                                                const int* __restrict__ dst1,
                                                int* __restrict__ bcnt, int nE)
{
    const int t = blockIdx.y;
    const int* dst = t ? dst1 : dst0;
    __shared__ int h[256];
    h[threadIdx.x] = 0;
    __syncthreads();
    for (int e = blockIdx.x * 256 + threadIdx.x; e < nE; e += gridDim.x * 256)
        atomicAdd(&h[dst[e] >> 8], 1);
    __syncthreads();
    if (h[threadIdx.x]) atomicAdd(&bcnt[t * 256 + threadIdx.x], h[threadIdx.x]);
}

__global__ __launch_bounds__(64) void bkt_scan(const int* __restrict__ bcnt,
                                               int* __restrict__ bbase,
                                               int* __restrict__ bcur,
                                               int* __restrict__ offs0,
                                               int* __restrict__ offs1, int N, int nE)
{
    if (threadIdx.x < 2) {
        int t = threadIdx.x;
        int run = 0;
        for (int i = 0; i < 256; ++i) {
            int v = bcnt[t * 256 + i];
            bbase[t * 256 + i] = run;
            bcur[t * 256 + i] = run;
            run += v;
        }
        if (t == 0) offs0[N] = nE; else offs1[N] = nE;
    }
}

__global__ __launch_bounds__(256) void bkt_part(const int* __restrict__ src0,
                                                const int* __restrict__ dst0,
                                                const int* __restrict__ src1,
                                                const int* __restrict__ dst1,
                                                int* __restrict__ bcur,
                                                unsigned* __restrict__ stage0,
                                                unsigned* __restrict__ stage1,
                                                int nE, int nbkt)
{
    const int t = blockIdx.y;
    const int* src = t ? src1 : src0;
    const int* dst = t ? dst1 : dst0;
    unsigned* stage = t ? stage1 : stage0;
    int* bc = bcur + t * 256;

    __shared__ unsigned ebuf[CHUNK];                   // 32 KB
    __shared__ int cnt[256], loff[256], cur[256], resv[256];

    const int tid  = threadIdx.x;
    const int e0   = blockIdx.x * CHUNK;
    const int ecnt = min(CHUNK, nE - e0);

    cnt[tid] = 0;
    __syncthreads();

    unsigned pk[CHUNK / 256];
    #pragma unroll
    for (int i = 0; i < CHUNK / 256; ++i) {
        const int le = i * 256 + tid;
        unsigned p = 0xFFFFFFFFu;
        if (le < ecnt) {
            int d = dst[e0 + le], s = src[e0 + le];
            p = ((unsigned)(d >> 8) << 24) | ((unsigned)(d & 255) << 16) | (unsigned)s;
            atomicAdd(&cnt[d >> 8], 1);
        }
        pk[i] = p;
    }
    __syncthreads();

    int v = cnt[tid];
    loff[tid] = v;
    __syncthreads();
    for (int off = 1; off < 256; off <<= 1) {
        int a = (tid >= off) ? loff[tid - off] : 0;
        __syncthreads();
        loff[tid] += a;
        __syncthreads();
    }
    int excl = loff[tid] - v;
    __syncthreads();
    loff[tid] = excl;
    cur[tid]  = excl;
    __syncthreads();

    #pragma unroll
    for (int i = 0; i < CHUNK / 256; ++i) {
        unsigned p = pk[i];
        if (p != 0xFFFFFFFFu) {
            int b = p >> 24;
            int pos = atomicAdd(&cur[b], 1);
            ebuf[pos] = p;
        }
    }
    __syncthreads();

    if (tid < nbkt && cnt[tid] > 0) resv[tid] = atomicAdd(&bc[tid], cnt[tid]);
    __syncthreads();

    const int wv = tid >> 6, ln = tid & 63;
    for (int b = wv; b < nbkt; b += 4) {
        const int c = cnt[b];
        if (c == 0) continue;
        const int lo = loff[b];
        const int rb = resv[b];
        for (int i = ln; i < c; i += 64) stage[rb + i] = ebuf[lo + i];
    }
}

__global__ __launch_bounds__(256) void bkt_fill(const unsigned* __restrict__ stage0,
                                                const unsigned* __restrict__ stage1,
                                                const int* __restrict__ bcnt,
                                                const int* __restrict__ bbase,
                                                int* __restrict__ offs0,
                                                int* __restrict__ offs1,
                                                int* __restrict__ col0,
                                                int* __restrict__ col1, int N)
{
    const int b = blockIdx.x, t = blockIdx.y;
    const unsigned* stage = t ? stage1 : stage0;
    int* offs = t ? offs1 : offs0;
    int* col  = t ? col1 : col0;
    const int base = bbase[t * 256 + b];
    int cb = bcnt[t * 256 + b];
    if (cb > CAP) cb = CAP;

    __shared__ unsigned ebuf[CAP];
    __shared__ int colbuf[CAP];
    __shared__ int dcnt[256], doff[256], dcur[256];

    const int tid = threadIdx.x;
    dcnt[tid] = 0;
    __syncthreads();

    for (int i = tid; i < cb; i += 256) {
        unsigned p = stage[base + i];
        ebuf[i] = p;
        atomicAdd(&dcnt[(p >> 16) & 255], 1);
    }
    __syncthreads();

    int v = dcnt[tid];
    doff[tid] = v;
    __syncthreads();
    for (int off = 1; off < 256; off <<= 1) {
        int a = (tid >= off) ? doff[tid - off] : 0;
        __syncthreads();
        doff[tid] += a;
        __syncthreads();
    }
    int excl = doff[tid] - v;
    dcur[tid] = excl;
    const int node = (b << 8) + tid;
    if (node < N) offs[node] = base + excl;
    __syncthreads();

    for (int i = tid; i < cb; i += 256) {
        unsigned p = ebuf[i];
        int pos = atomicAdd(&dcur[(p >> 16) & 255], 1);
        colbuf[pos] = (int)(p & 0xFFFFu);
    }
    __syncthreads();

    for (int i = tid; i < cb; i += 256) col[base + i] = colbuf[i];
}

// ==================== fused attention: 16 lanes/edge, 4 edges in flight ====================
template<bool BF16_OUT>
__global__ __launch_bounds__(256) void attn_gather(const ushort* __restrict__ QV,
                                                   const ushort* __restrict__ K,
                                                   const int* __restrict__ offs,
                                                   const int* __restrict__ col,
                                                   void* __restrict__ outv, int n)
{
    const int wid  = (blockIdx.x * 256 + threadIdx.x) >> 6;
    const int lane = threadIdx.x & 63;
    if (wid >= n) return;
    const int li = lane & 15;
    const int g  = lane >> 4;

    const int beg = offs[wid], end = offs[wid + 1];

    uint4 ku = ((const uint4*)(K + (size_t)wid * DD))[li];
    float kf[8];
    {
        float2 t;
        t = bfp(ku.x); kf[0]=t.x; kf[1]=t.y;
        t = bfp(ku.y); kf[2]=t.x; kf[3]=t.y;
        t = bfp(ku.z); kf[4]=t.x; kf[5]=t.y;
        t = bfp(ku.w); kf[6]=t.x; kf[7]=t.y;
    }

    float m = -__builtin_inff();
    float den = 0.f;
    float acc[8] = {0.f,0.f,0.f,0.f,0.f,0.f,0.f,0.f};

    int p = beg + g;
    uint4 qn = make_uint4(0,0,0,0), vn = make_uint4(0,0,0,0);
    if (p < end) {
        const ushort* row = QV + (size_t)col[p] * 256;
        qn = ((const uint4*)row)[li];
        vn = ((const uint4*)(row + 128))[li];
    }

    while (p < end) {
        uint4 qu = qn, vu = vn;
        const int pn = p + 4;
        if (pn < end) {
            const ushort* row = QV + (size_t)col[pn] * 256;
            qn = ((const uint4*)row)[li];
            vn = ((const uint4*)(row + 128))[li];
        }
        float2 t;
        float d;
        t = bfp(qu.x); d  = t.x*kf[0] + t.y*kf[1];
        t = bfp(qu.y); d += t.x*kf[2] + t.y*kf[3];
        t = bfp(qu.z); d += t.x*kf[4] + t.y*kf[5];
        t = bfp(qu.w); d += t.x*kf[6] + t.y*kf[7];
        d += __shfl_xor(d, 1);
        d += __shfl_xor(d, 2);
        d += __shfl_xor(d, 4);
        d += __shfl_xor(d, 8);
        float sc = d * 0.08838834764831845f;      // 1/sqrt(128)
        sc = sc > 0.f ? sc : 0.01f * sc;          // leaky_relu
        float nm = fmaxf(m, sc);
        float f  = __expf(m - nm);                // first iter: exp(-inf)=0
        float pe = __expf(sc - nm);
        den = den * f + pe;
        float2 v0 = bfp(vu.x), v1 = bfp(vu.y), v2 = bfp(vu.z), v3 = bfp(vu.w);
        acc[0] = acc[0]*f + pe*v0.x;  acc[1] = acc[1]*f + pe*v0.y;
        acc[2] = acc[2]*f + pe*v1.x;  acc[3] = acc[3]*f + pe*v1.y;
        acc[4] = acc[4]*f + pe*v2.x;  acc[5] = acc[5]*f + pe*v2.y;
        acc[6] = acc[6]*f + pe*v3.x;  acc[7] = acc[7]*f + pe*v3.y;
        m = nm;
        p = pn;
    }

    // merge the 4 groups
    float m1 = fmaxf(m, __shfl_xor(m, 16));
    float m2 = fmaxf(m1, __shfl_xor(m1, 32));
    float f = (den > 0.f) ? __expf(m - m2) : 0.f;   // guard -inf - -inf
    den *= f;
    den += __shfl_xor(den, 16);
    den += __shfl_xor(den, 32);
    #pragma unroll
    for (int j = 0; j < 8; ++j) {
        acc[j] *= f;
        acc[j] += __shfl_xor(acc[j], 16);
        acc[j] += __shfl_xor(acc[j], 32);
    }
    if (g == 0) {
        const float inv = den > 0.f ? 1.f / den : 0.f;
        if (BF16_OUT) {
            ushort* o = (ushort*)outv + (size_t)wid * DD + li * 8;
            bf16x8 h;
            #pragma unroll
            for (int j = 0; j < 8; ++j) h[j] = (short)f2bf(acc[j] * inv);
            *(bf16x8*)o = h;
        } else {
            float* o = (float*)outv + (size_t)wid * DD + li * 8;
            *(float4*)o       = make_float4(acc[0]*inv, acc[1]*inv, acc[2]*inv, acc[3]*inv);
            *(float4*)(o + 4) = make_float4(acc[4]*inv, acc[5]*inv, acc[6]*inv, acc[7]*inv);
        }
    }
}

// ==================== host ====================
extern "C" void kernel_launch(void* const* d_in, const int* in_sizes, int n_in,
                              void* d_out, int out_size, void* d_ws, size_t ws_size,
                              hipStream_t stream)
{
    const float* x_a    = (const float*)d_in[0];
    const float* x_b    = (const float*)d_in[1];
    const int*   ei_ab  = (const int*)d_in[2];
    const int*   ei_ba  = (const int*)d_in[3];
    const float* qkv_w  = (const float*)d_in[4];
    const float* qkv_b  = (const float*)d_in[5];
    const float* edge_W = (const float*)d_in[6];
    float* out = (float*)d_out;

    const int N = in_sizes[0] / DD;    // 50000
    const int E = in_sizes[2] / 2;     // 600000
    const int nbkt = (N + 255) >> 8;   // 196

    float* ws = (float*)d_ws;
    float* WC  = ws;                         // 4*128*128 f32
    float* BCq = WC + 4 * DD * DD;           // 4*128 f32
    float* B3  = BCq + 4 * DD;               // 4*384 f32
    ushort* W3P = (ushort*)(B3 + 4 * 384);   // 4*49152 bf16
    ushort* HA  = W3P + (size_t)4 * 49152;   // layer-1 out a bf16 [N*128]
    ushort* HB  = HA + (size_t)N * DD;       // layer-1 out b bf16
    ushort* QVa = HB + (size_t)N * DD;       // q|v type a [N*256] bf16
    ushort* QVb = QVa + (size_t)N * 256;     // q|v type b
    ushort* FKa = QVb + (size_t)N * 256;     // k type a [N*128] bf16
    ushort* FKb = FKa + (size_t)N * DD;      // k type b
    int* ip      = (int*)(FKb + (size_t)N * DD);
    int* bcnt    = ip;                           // [512]
    int* bbase   = bcnt + 512;                   // [512]
    int* bcur    = bbase + 512;                  // [512]
    int* offs_ab = bcur + 512;                   // [N+1]
    int* offs_ba = offs_ab + (N + 1);            // [N+1]
    int* col_ab  = offs_ba + (N + 1);            // [E]
    int* col_ba  = col_ab + E;                   // [E]
    unsigned* stage0 = (unsigned*)(col_ba + E);  // [E]
    unsigned* stage1 = stage0 + E;               // [E]

    // ---- weight prep ----
    {
        dim3 g1(64, 4);
        combine_all<<<g1, 256, 0, stream>>>(qkv_w, qkv_b, edge_W, WC, BCq);
        dim3 g2(24, 4);
        pack_all<<<g2, 256, 0, stream>>>(qkv_w, qkv_b, WC, BCq, W3P, B3);
    }

    // ---- CSR via two-level bucket sort (reused by both layers) ----
    const int* s_ab = ei_ab;  const int* d_ab = ei_ab + E;
    const int* s_ba = ei_ba;  const int* d_ba = ei_ba + E;
    {
        zero_ints<<<2, 256, 0, stream>>>(bcnt, 512);
        dim3 hg(128, 2);
        bkt_hist<<<hg, 256, 0, stream>>>(d_ab, d_ba, bcnt, E);
        bkt_scan<<<1, 64, 0, stream>>>(bcnt, bbase, bcur, offs_ab, offs_ba, N, E);
        dim3 pg((E + CHUNK - 1) / CHUNK, 2);
        bkt_part<<<pg, 256, 0, stream>>>(s_ab, d_ab, s_ba, d_ba, bcur,
                                         stage0, stage1, E, nbkt);
        dim3 fg(nbkt, 2);
        bkt_fill<<<fg, 256, 0, stream>>>(stage0, stage1, bcnt, bbase,
                                         offs_ab, offs_ba, col_ab, col_ba, N);
    }

    const dim3 gemm_grid((N + 63) / 64, 6);
    const int ag_grid = (N + 3) / 4;

    // ---- layer 1: per-plane GEMM (f32 inputs, B in LDS), two attends (bf16 H out) ----
    gemm_mfma<true, false><<<gemm_grid, 256, 0, stream>>>(
        x_a, x_b, W3P, B3, QVa, FKa, QVb, FKb, N);
    attn_gather<true><<<ag_grid, 256, 0, stream>>>(QVa, FKb, offs_ab, col_ab, HB, N);
    attn_gather<true><<<ag_grid, 256, 0, stream>>>(QVb, FKa, offs_ba, col_ba, HA, N);

    // ---- layer 2: per-plane GEMM (bf16+relu inputs), two attends (f32 out) ----
    float* o_a = out;
    float* o_b = out + (size_t)N * DD;
    gemm_mfma<false, true><<<gemm_grid, 256, 0, stream>>>(
        HA, HB, W3P + (size_t)2 * 49152, B3 + 2 * 384, QVa, FKa, QVb, FKb, N);
    attn_gather<false><<<ag_grid, 256, 0, stream>>>(QVa, FKb, offs_ab, col_ab, o_b, N);
    attn_gather<false><<<ag_grid, 256, 0, stream>>>(QVb, FKa, offs_ba, col_ba, o_a, N);
}